// Round 8
// baseline (316.100 us; speedup 1.0000x reference)
//
#include <hip/hip_runtime.h>
#include <hip/hip_bf16.h>

// x: [2, 2048, 1024] f32; mask: [2, 2048, 2048] f32; W_qkv: [1024, 3072] f32
// W_out: [1024, 1024] f32; b_out: [1024] f32; out: [2, 2048, 1024] f32
#define BATCH 2
#define SEQ   2048
#define DIM   1024
#define HEADS 16
#define DH    64
#define N_QKV 3072
#define M_TOT 4096
#define SCALE 0.125f
#define EPS   1e-10f
#define LOG2E 1.442695041f

typedef __attribute__((ext_vector_type(8))) _Float16 half8;
typedef __attribute__((ext_vector_type(4))) float f32x4;

static __device__ __forceinline__ unsigned short f2h(float f) {
    _Float16 h = (_Float16)f;
    return __builtin_bit_cast(unsigned short, h);
}
static __device__ __forceinline__ unsigned int pkrtz(float a, float b) {
#if defined(__has_builtin) && __has_builtin(__builtin_amdgcn_cvt_pkrtz)
    return __builtin_bit_cast(unsigned int, __builtin_amdgcn_cvt_pkrtz(a, b));
#else
    return (unsigned int)f2h(a) | ((unsigned int)f2h(b) << 16);
#endif
}
static __device__ __forceinline__ void glds16(const void* g, void* l) {
    __builtin_amdgcn_global_load_lds((const __attribute__((address_space(1))) void*)g,
                                     (__attribute__((address_space(3))) void*)l,
                                     16, 0, 0);
}

// ---------------------------------------------------------------------------
// Merged pre-pass (r15): one launch, 4 independent jobs by block range.
// ---------------------------------------------------------------------------
__global__ __launch_bounds__(256) void prepass(const float* __restrict__ x,
                                               unsigned short* __restrict__ xh,
                                               const float* __restrict__ Wq,
                                               unsigned short* __restrict__ WqT,
                                               const float* __restrict__ Wo,
                                               unsigned short* __restrict__ WoT,
                                               const float* __restrict__ mask,
                                               unsigned short* __restrict__ mbits) {
    const int bid = blockIdx.x;
    const int t   = threadIdx.x;
    __shared__ float tile[32][33];
    __shared__ unsigned char flags[16][256];

    if (bid < 4096) {
        const int i = bid * 256 + t;
        float4 v = reinterpret_cast<const float4*>(x)[i];
        uint2 o;
        o.x = pkrtz(v.x, v.y);
        o.y = pkrtz(v.z, v.w);
        reinterpret_cast<uint2*>(xh)[i] = o;
    } else if (bid < 8192) {
        const float* src; unsigned short* th; int rows, cols, bx;
        if (bid < 7168) { src = Wq; th = WqT; rows = 1024; cols = 3072; bx = bid - 4096;
        } else          { src = Wo; th = WoT; rows = 1024; cols = 1024; bx = bid - 7168; }
        const int nbx = cols / 32;
        const int c0 = (bx % nbx) * 32, r0 = (bx / nbx) * 32;
        const int tx = t & 31, ty = t >> 5;
        #pragma unroll
        for (int i = ty; i < 32; i += 8)
            tile[i][tx] = src[(long)(r0 + i) * cols + c0 + tx];
        __syncthreads();
        #pragma unroll
        for (int i = ty; i < 32; i += 8)
            th[(long)(c0 + i) * rows + r0 + tx] = f2h(tile[tx][i]);
    } else {
        const int bx = bid - 8192;
        const int it = bx & 127;
        const int bb = bx >> 7;
        const int R0 = it * 16;
        const int tl = t >> 6, ln = t & 63;
        for (int c0 = 0; c0 < SEQ; c0 += 256) {
            #pragma unroll
            for (int rr = 0; rr < 16; ++rr)
                flags[rr][t] = mask[((long)bb * SEQ + R0 + rr) * SEQ + c0 + t] != 0.f;
            __syncthreads();
            unsigned int bits = 0;
            #pragma unroll
            for (int nt = 0; nt < 4; ++nt)
                #pragma unroll
                for (int r = 0; r < 4; ++r)
                    bits |= (unsigned int)flags[ln & 15][tl * 64 + nt * 16 + ((ln >> 4) << 2) + r]
                            << (nt * 4 + r);
            mbits[(((long)bb * 128 + it) * 32 + (c0 >> 6) + tl) * 64 + ln] = (unsigned short)bits;
            __syncthreads();
        }
    }
}

// ---------------------------------------------------------------------------
// GEMM 1 v5 (round-2 verified): 128x128 tile, BK=64, glds16 + 2-phase,
// XOR-swizzled LDS. Grid 24x32 = 768 blocks = 3/CU all-resident.
// ---------------------------------------------------------------------------
__global__ __launch_bounds__(256, 3) void gemm_qkv_f16(
    const unsigned short* __restrict__ Ahg, const unsigned short* __restrict__ Bhg,
    unsigned short* __restrict__ qb, unsigned short* __restrict__ kb,
    unsigned short* __restrict__ vtb) {
    __shared__ __align__(16) unsigned short As[128 * 64];   // 16 KB
    __shared__ __align__(16) unsigned short Bs[128 * 64];   // 16 KB

    const int n0   = blockIdx.x * 128;
    const int m0   = blockIdx.y * 128;
    const int wave = threadIdx.x >> 6;
    const int lane = threadIdx.x & 63;
    const int l16  = lane & 15;
    const int g    = lane >> 4;
    const int wm   = wave & 1;
    const int wn   = wave >> 1;
    const int sw   = l16 & 7;

    const int sr8 = lane >> 3;
    const int scg = (lane & 7) ^ sr8;

    f32x4 acc[4][4] = {};

    for (int k0 = 0; k0 < DIM; k0 += 64) {
        #pragma unroll
        for (int i = 0; i < 4; ++i) {
            const int row = wave * 32 + i * 8;     // wave-uniform; covers 0..127
            glds16(Ahg + (long)(m0 + row + sr8) * DIM + k0 + scg * 8, &As[row * 64]);
            glds16(Bhg + (long)(n0 + row + sr8) * DIM + k0 + scg * 8, &Bs[row * 64]);
        }
        __syncthreads();

        #pragma unroll
        for (int kc = 0; kc < 2; ++kc) {
            half8 a[4], b[4];
            #pragma unroll
            for (int mt = 0; mt < 4; ++mt)
                a[mt] = *reinterpret_cast<const half8*>(
                    &As[(wm * 64 + mt * 16 + l16) * 64 + (((kc * 4 + g) ^ sw) * 8)]);
            #pragma unroll
            for (int nt = 0; nt < 4; ++nt)
                b[nt] = *reinterpret_cast<const half8*>(
                    &Bs[(wn * 64 + nt * 16 + l16) * 64 + (((kc * 4 + g) ^ sw) * 8)]);
            #pragma unroll
            for (int mt = 0; mt < 4; ++mt)
                #pragma unroll
                for (int nt = 0; nt < 4; ++nt)
                    acc[mt][nt] = __builtin_amdgcn_mfma_f32_16x16x32_f16(
                        a[mt], b[nt], acc[mt][nt], 0, 0, 0);
        }
        __syncthreads();
    }

    #pragma unroll
    for (int nt = 0; nt < 4; ++nt) {
        const int n     = n0 + wn * 64 + nt * 16 + l16;
        const int which = n >> 10;                 // block-uniform (1024 % 128 == 0)
        const int rem   = n & 1023;
        const int head  = rem >> 6;
        const int d     = rem & 63;
        #pragma unroll
        for (int mt = 0; mt < 4; ++mt) {
            #pragma unroll
            for (int r = 0; r < 4; ++r) {
                const int m  = m0 + wm * 64 + mt * 16 + g * 4 + r;
                const int bb = m >> 11;
                const int li = m & 2047;
                const int bh_i = bb * HEADS + head;
                const float val = acc[mt][nt][r];
                if (which == 0)
                    qb[((long)bh_i * SEQ + li) * DH + d] = f2h(val * (SCALE * LOG2E));
                else if (which == 1)
                    kb[((long)bh_i * SEQ + li) * DH + d] = f2h(val);
                else
                    vtb[((long)bh_i * DH + d) * SEQ + li] = f2h(val);
            }
        }
    }
}

// ---------------------------------------------------------------------------
// GEMM 2 (round-0 verified): glds16 + __syncthreads, 64x64 tiles, 4/CU.
// ---------------------------------------------------------------------------
__global__ __launch_bounds__(256, 4) void gemm_out_f16(
    const unsigned short* __restrict__ Ahg, const unsigned short* __restrict__ Bhg,
    const float* __restrict__ bias, float* __restrict__ out) {
    __shared__ __align__(16) unsigned short As[64 * 64];
    __shared__ __align__(16) unsigned short Bs[64 * 64];

    const int n0   = blockIdx.x * 64;
    const int m0   = blockIdx.y * 64;
    const int wave = threadIdx.x >> 6;
    const int lane = threadIdx.x & 63;
    const int l16  = lane & 15;
    const int g    = lane >> 4;
    const int wm   = wave & 1;
    const int wn   = wave >> 1;
    const int sw   = l16 & 7;

    const int sr8 = lane >> 3;
    const int scg = (lane & 7) ^ sr8;

    f32x4 acc[2][2] = {};

    for (int k0 = 0; k0 < DIM; k0 += 64) {
        #pragma unroll
        for (int i = 0; i < 2; ++i) {
            const int row = wave * 16 + i * 8;
            glds16(Ahg + (long)(m0 + row + sr8) * DIM + k0 + scg * 8, &As[row * 64]);
            glds16(Bhg + (long)(n0 + row + sr8) * DIM + k0 + scg * 8, &Bs[row * 64]);
        }
        __syncthreads();

        half8 a[2][2];
        #pragma unroll
        for (int mt = 0; mt < 2; ++mt) {
            const int rbase = (wm * 32 + mt * 16 + l16) * 64;
            #pragma unroll
            for (int kc = 0; kc < 2; ++kc)
                a[mt][kc] = *reinterpret_cast<const half8*>(
                    &As[rbase + (((kc * 4 + g) ^ sw) * 8)]);
        }
        #pragma unroll
        for (int nt = 0; nt < 2; ++nt) {
            const int rbase = (wn * 32 + nt * 16 + l16) * 64;
            const half8 b0 = *reinterpret_cast<const half8*>(&Bs[rbase + (((0 + g) ^ sw) * 8)]);
            const half8 b1 = *reinterpret_cast<const half8*>(&Bs[rbase + (((4 + g) ^ sw) * 8)]);
            #pragma unroll
            for (int mt = 0; mt < 2; ++mt) {
                acc[mt][nt] = __builtin_amdgcn_mfma_f32_16x16x32_f16(a[mt][0], b0, acc[mt][nt], 0, 0, 0);
                acc[mt][nt] = __builtin_amdgcn_mfma_f32_16x16x32_f16(a[mt][1], b1, acc[mt][nt], 0, 0, 0);
            }
        }
        __syncthreads();
    }

    #pragma unroll
    for (int nt = 0; nt < 2; ++nt) {
        const int n  = n0 + wn * 32 + nt * 16 + l16;
        const float bv = bias[n];
        #pragma unroll
        for (int mt = 0; mt < 2; ++mt) {
            #pragma unroll
            for (int r = 0; r < 4; ++r) {
                const int m = m0 + wm * 32 + mt * 16 + g * 4 + r;
                out[(long)m * DIM + n] = acc[mt][nt][r] + bv;
            }
        }
    }
}

// ---------------------------------------------------------------------------
// MFMA flash attention v13 (resubmitted; round-7 bench was an infra failure):
// round-4 v10 compute structure (8 waves, 128 q-rows/block, 512 blocks —
// best measured, 61.2 us) with two verified add-ons:
//  1. P-overwrite trick (round-6-verified-correct): ONE 2KB P buffer/wave;
//     tile1's packed P parked in 8 VGPRs until tile0's fragments consumed.
//     LDS 64 -> 48 KB => 3 blocks/CU (was 2): 6 waves/SIMD of latency cover.
//  2. XCD-clustered flat grid (round-5/6 verified: FETCH collapses to ~ideal):
//     all 16 qt-blocks of one (bb,h) on one XCD => staging glds16 L2-hits.
// __launch_bounds__(512,6) caps VGPR at 85 (measured 64 on the r6 p1s
// variant -> no spill) so VGPR can't cap occupancy below the LDS-bound 6/SIMD.
// ---------------------------------------------------------------------------
__global__ __launch_bounds__(512, 6) void attn_mfma(const unsigned short* __restrict__ qb,
                                                    const unsigned short* __restrict__ kb,
                                                    const unsigned short* __restrict__ vtb,
                                                    const unsigned short* __restrict__ mbits,
                                                    unsigned short* __restrict__ zh) {
    // XCD-clustered decode: flat%8 = XCD; 16 qt-blocks of (bb,h) share an XCD.
    const int flat = blockIdx.x;            // 0..511
    const int xcd  = flat & 7;
    const int rr   = flat >> 3;             // 0..63
    const int hh   = xcd + 8 * (rr >> 4);   // 0..31 packed (bb*16+h)
    const int qt   = rr & 15;               // 128 q-rows each
    const int h    = hh & 15;
    const int bb   = hh >> 4;
    const int bh   = bb * HEADS + h;
    const int wave = threadIdx.x >> 6;      // 0..7
    const int lane = threadIdx.x & 63;
    const int l16  = lane & 15;
    const int g    = lane >> 4;
    const int wm   = wave >> 1;             // row group 0..3 (32 rows each)
    const int wj   = wave & 1;              // j half

    const int myrow0 = qt * 128 + wm * 32;

    // 48 KB: [0,16384) KV shorts (wj*8192 + {K:0,V:4096} + off)
    //        [16384,24576) per-wave P (wave*1024 + off)
    // epilogue reuses [0, 8832 floats) = 35 KB as cmb.
    __shared__ __align__(16) unsigned short shm[24576];
    unsigned short* Ks = &shm[wj * 8192];
    unsigned short* Vs = &shm[wj * 8192 + 4096];
    unsigned short* Pw = &shm[16384 + wave * 1024];

    const int sr8 = lane >> 3;
    const int scg = (lane & 7) ^ sr8;
    const int sw  = l16 & 7;

    const unsigned short* qptr = qb + ((long)bh * SEQ + myrow0 + l16) * DH + g * 8;
    const half8 q0 = *reinterpret_cast<const half8*>(qptr);
    const half8 q1 = *reinterpret_cast<const half8*>(qptr + 32);
    const half8 q2 = *reinterpret_cast<const half8*>(qptr + 16 * DH);
    const half8 q3 = *reinterpret_cast<const half8*>(qptr + 16 * DH + 32);

    half8 ones;
    #pragma unroll
    for (int j = 0; j < 8; ++j) ones[j] = (_Float16)1.0f;

    f32x4 o0[4] = {}, o1[4] = {};
    f32x4 oz0 = {0.f, 0.f, 0.f, 0.f};
    f32x4 oz1 = {0.f, 0.f, 0.f, 0.f};

    const unsigned short* mb =
        mbits + (((long)bb * 128 + qt * 8 + wm * 2) * 32 + wj * 16) * 64 + lane;
    const long kbase = (long)bh * SEQ * DH;
    const long vbase = (long)bh * DH * SEQ;
    const int  jb    = wj * 1024;

    for (int it = 0; it < 16; ++it) {
        const int j0 = jb + it * 64;
        const unsigned int bits0 = mb[(long)it * 64];
        const unsigned int bits1 = mb[(long)it * 64 + 2048];

        // ---- stage K/V tile (per wj half): 4 waves cover rows 0..63 ----
        #pragma unroll
        for (int i = 0; i < 2; ++i) {
            const int row = wm * 16 + i * 8;           // wave-uniform
            glds16(kb  + kbase + (long)(j0 + row + sr8) * DH + scg * 8, Ks + row * 64);
            glds16(vtb + vbase + (long)(row + sr8) * SEQ + j0 + scg * 8, Vs + row * 64);
        }
        __syncthreads();

        // ---- S^T = K Q^T both q-tiles; softmax fused; tile0 P -> LDS,
        //      tile1 P packed in regs ----
        uint2 p1s[4];
        #pragma unroll
        for (int nt = 0; nt < 4; ++nt) {
            const int rbase = (nt * 16 + l16) * 64;
            const half8 k0 = *reinterpret_cast<const half8*>(&Ks[rbase + ((0 + g) ^ sw) * 8]);
            const half8 k1 = *reinterpret_cast<const half8*>(&Ks[rbase + (((4 + g) ^ sw) * 8)]);
            f32x4 s0 = {0.f, 0.f, 0.f, 0.f};
            f32x4 s1 = {0.f, 0.f, 0.f, 0.f};
            s0 = __builtin_amdgcn_mfma_f32_16x16x32_f16(k0, q0, s0, 0, 0, 0);
            s0 = __builtin_amdgcn_mfma_f32_16x16x32_f16(k1, q1, s0, 0, 0, 0);
            s1 = __builtin_amdgcn_mfma_f32_16x16x32_f16(k0, q2, s1, 0, 0, 0);
            s1 = __builtin_amdgcn_mfma_f32_16x16x32_f16(k1, q3, s1, 0, 0, 0);

            float pa[4], pb[4];
            #pragma unroll
            for (int r = 0; r < 4; ++r) {
                const float e0 = __builtin_amdgcn_exp2f(s0[r]);
                const float e1 = __builtin_amdgcn_exp2f(s1[r]);
                pa[r] = ((bits0 >> (nt * 4 + r)) & 1u) ? e0 : 0.f;
                pb[r] = ((bits1 >> (nt * 4 + r)) & 1u) ? e1 : 0.f;
            }
            const int poff = l16 * 64 + (((2 * nt + (g >> 1)) ^ sw) * 8) + (g & 1) * 4;
            uint2 pk0;
            pk0.x = pkrtz(pa[0], pa[1]);
            pk0.y = pkrtz(pa[2], pa[3]);
            *reinterpret_cast<uint2*>(&Pw[poff]) = pk0;
            p1s[nt].x = pkrtz(pb[0], pb[1]);
            p1s[nt].y = pkrtz(pb[2], pb[3]);
        }

        // ---- tile0 P fragments, then overwrite Pw with tile1 (wave-private,
        //      lgkm-ordered: reads complete before aliasing writes) ----
        const half8 pb00 = *reinterpret_cast<const half8*>(&Pw[l16 * 64 + ((0 + g) ^ sw) * 8]);
        const half8 pb01 = *reinterpret_cast<const half8*>(&Pw[l16 * 64 + (((4 + g) ^ sw) * 8)]);
        #pragma unroll
        for (int nt = 0; nt < 4; ++nt) {
            const int poff = l16 * 64 + (((2 * nt + (g >> 1)) ^ sw) * 8) + (g & 1) * 4;
            *reinterpret_cast<uint2*>(&Pw[poff]) = p1s[nt];
        }
        const half8 pb10 = *reinterpret_cast<const half8*>(&Pw[l16 * 64 + ((0 + g) ^ sw) * 8]);
        const half8 pb11 = *reinterpret_cast<const half8*>(&Pw[l16 * 64 + (((4 + g) ^ sw) * 8)]);

        // ---- V fragments once; each feeds both q-tiles' PV ----
        #pragma unroll
        for (int dt = 0; dt < 4; ++dt) {
            const int vb = (dt * 16 + l16) * 64;
            const half8 v0 = *reinterpret_cast<const half8*>(&Vs[vb + ((0 + g) ^ sw) * 8]);
            const half8 v1 = *reinterpret_cast<const half8*>(&Vs[vb + (((4 + g) ^ sw) * 8)]);
            o0[dt] = __builtin_amdgcn_mfma_f32_16x16x32_f16(v0, pb00, o0[dt], 0, 0, 0);
            o0[dt] = __builtin_amdgcn_mfma_f32_16x16x32_f16(v1, pb01, o0[dt], 0, 0, 0);
            o1[dt] = __builtin_amdgcn_mfma_f32_16x16x32_f16(v0, pb10, o1[dt], 0, 0, 0);
            o1[dt] = __builtin_amdgcn_mfma_f32_16x16x32_f16(v1, pb11, o1[dt], 0, 0, 0);
        }
        oz0 = __builtin_amdgcn_mfma_f32_16x16x32_f16(ones, pb00, oz0, 0, 0, 0);
        oz0 = __builtin_amdgcn_mfma_f32_16x16x32_f16(ones, pb01, oz0, 0, 0, 0);
        oz1 = __builtin_amdgcn_mfma_f32_16x16x32_f16(ones, pb10, oz1, 0, 0, 0);
        oz1 = __builtin_amdgcn_mfma_f32_16x16x32_f16(ones, pb11, oz1, 0, 0, 0);
        __syncthreads();    // release KV tile for next staging round
    }

    // ---- combine the two j-halves (linear partials) ----
    float* cmb = (float*)shm;               // 128*68 + 128 floats = 35 KB <= 48 KB
    const int ZOFF = 128 * 68;
    const int ci0  = wm * 32 + l16;
    const int ci1  = ci0 + 16;
    if (wj == 1) {
        #pragma unroll
        for (int dt = 0; dt < 4; ++dt) {
            *reinterpret_cast<f32x4*>(&cmb[ci0 * 68 + dt * 16 + g * 4]) = o0[dt];
            *reinterpret_cast<f32x4*>(&cmb[ci1 * 68 + dt * 16 + g * 4]) = o1[dt];
        }
        if (g == 0) {
            cmb[ZOFF + ci0] = oz0[0];
            cmb[ZOFF + ci1] = oz1[0];
        }
    }
    __syncthreads();
    if (wj == 0) {
        const float Z0   = oz0[0] + cmb[ZOFF + ci0];
        const float Z1   = oz1[0] + cmb[ZOFF + ci1];
        const float inv0 = 1.f / (Z0 + 1e-30f);
        const float inv1 = 1.f / (Z1 + 1e-30f);
        const long obase0 = ((long)bb * SEQ + myrow0 + l16) * DIM + h * DH;
        const long obase1 = obase0 + (long)16 * DIM;
        #pragma unroll
        for (int dt = 0; dt < 4; ++dt) {
            const f32x4 oc0 = *reinterpret_cast<const f32x4*>(&cmb[ci0 * 68 + dt * 16 + g * 4]);
            const f32x4 oc1 = *reinterpret_cast<const f32x4*>(&cmb[ci1 * 68 + dt * 16 + g * 4]);
            uint2 pk;
            pk.x = pkrtz((o0[dt][0] + oc0[0]) * inv0, (o0[dt][1] + oc0[1]) * inv0);
            pk.y = pkrtz((o0[dt][2] + oc0[2]) * inv0, (o0[dt][3] + oc0[3]) * inv0);
            *reinterpret_cast<uint2*>(zh + obase0 + dt * 16 + g * 4) = pk;
            pk.x = pkrtz((o1[dt][0] + oc1[0]) * inv1, (o1[dt][1] + oc1[1]) * inv1);
            pk.y = pkrtz((o1[dt][2] + oc1[2]) * inv1, (o1[dt][3] + oc1[3]) * inv1);
            *reinterpret_cast<uint2*>(zh + obase1 + dt * 16 + g * 4) = pk;
        }
    }
}

// ---------------------------------------------------------------------------
extern "C" void kernel_launch(void* const* d_in, const int* in_sizes, int n_in,
                              void* d_out, int out_size, void* d_ws, size_t ws_size,
                              hipStream_t stream) {
    const float* x     = (const float*)d_in[0];
    const float* mask  = (const float*)d_in[1];
    const float* W_qkv = (const float*)d_in[2];
    const float* W_out = (const float*)d_in[3];
    const float* b_out = (const float*)d_in[4];
    float* out = (float*)d_out;

    unsigned short* ws = (unsigned short*)d_ws;
    unsigned short* xh    = ws;                  // 4M fp16 (reused as z after gemm1)
    unsigned short* WqT   = xh    + 4194304;     // 3M fp16
    unsigned short* WoT   = WqT   + 3145728;     // 1M fp16
    unsigned short* qbu   = WoT   + 1048576;     // 4M fp16
    unsigned short* kbu   = qbu   + 4194304;     // 4M fp16
    unsigned short* vtb   = kbu   + 4194304;     // 4M fp16
    unsigned short* mbits = vtb   + 4194304;     // 0.5M -> 41 MB total
    unsigned short* zz    = xh;

    prepass<<<8448, 256, 0, stream>>>(x, xh, W_qkv, WqT, W_out, WoT, mask, mbits);

    gemm_qkv_f16<<<dim3(24, 32), 256, 0, stream>>>(xh, WqT, qbu, kbu, vtb);

    attn_mfma<<<512, 512, 0, stream>>>(qbu, kbu, vtb, mbits, zz);

    gemm_out_f16<<<dim3(16, 64), 256, 0, stream>>>(zz, WoT, b_out, out);
}

// Round 9
// 232.938 us; speedup vs baseline: 1.3570x; 1.3570x over previous
//
#include <hip/hip_runtime.h>
#include <hip/hip_bf16.h>

// x: [2, 2048, 1024] f32; mask: [2, 2048, 2048] f32; W_qkv: [1024, 3072] f32
// W_out: [1024, 1024] f32; b_out: [1024] f32; out: [2, 2048, 1024] f32
#define BATCH 2
#define SEQ   2048
#define DIM   1024
#define HEADS 16
#define DH    64
#define N_QKV 3072
#define M_TOT 4096
#define SCALE 0.125f
#define EPS   1e-10f
#define LOG2E 1.442695041f

typedef __attribute__((ext_vector_type(8))) _Float16 half8;
typedef __attribute__((ext_vector_type(4))) float f32x4;

static __device__ __forceinline__ unsigned short f2h(float f) {
    _Float16 h = (_Float16)f;
    return __builtin_bit_cast(unsigned short, h);
}
static __device__ __forceinline__ unsigned int pkrtz(float a, float b) {
#if defined(__has_builtin) && __has_builtin(__builtin_amdgcn_cvt_pkrtz)
    return __builtin_bit_cast(unsigned int, __builtin_amdgcn_cvt_pkrtz(a, b));
#else
    return (unsigned int)f2h(a) | ((unsigned int)f2h(b) << 16);
#endif
}
static __device__ __forceinline__ void glds16(const void* g, void* l) {
    __builtin_amdgcn_global_load_lds((const __attribute__((address_space(1))) void*)g,
                                     (__attribute__((address_space(3))) void*)l,
                                     16, 0, 0);
}

// ---------------------------------------------------------------------------
// Merged pre-pass (r15): one launch, 4 independent jobs by block range.
// ---------------------------------------------------------------------------
__global__ __launch_bounds__(256) void prepass(const float* __restrict__ x,
                                               unsigned short* __restrict__ xh,
                                               const float* __restrict__ Wq,
                                               unsigned short* __restrict__ WqT,
                                               const float* __restrict__ Wo,
                                               unsigned short* __restrict__ WoT,
                                               const float* __restrict__ mask,
                                               unsigned short* __restrict__ mbits) {
    const int bid = blockIdx.x;
    const int t   = threadIdx.x;
    __shared__ float tile[32][33];
    __shared__ unsigned char flags[16][256];

    if (bid < 4096) {
        const int i = bid * 256 + t;
        float4 v = reinterpret_cast<const float4*>(x)[i];
        uint2 o;
        o.x = pkrtz(v.x, v.y);
        o.y = pkrtz(v.z, v.w);
        reinterpret_cast<uint2*>(xh)[i] = o;
    } else if (bid < 8192) {
        const float* src; unsigned short* th; int rows, cols, bx;
        if (bid < 7168) { src = Wq; th = WqT; rows = 1024; cols = 3072; bx = bid - 4096;
        } else          { src = Wo; th = WoT; rows = 1024; cols = 1024; bx = bid - 7168; }
        const int nbx = cols / 32;
        const int c0 = (bx % nbx) * 32, r0 = (bx / nbx) * 32;
        const int tx = t & 31, ty = t >> 5;
        #pragma unroll
        for (int i = ty; i < 32; i += 8)
            tile[i][tx] = src[(long)(r0 + i) * cols + c0 + tx];
        __syncthreads();
        #pragma unroll
        for (int i = ty; i < 32; i += 8)
            th[(long)(c0 + i) * rows + r0 + tx] = f2h(tile[tx][i]);
    } else {
        const int bx = bid - 8192;
        const int it = bx & 127;
        const int bb = bx >> 7;
        const int R0 = it * 16;
        const int tl = t >> 6, ln = t & 63;
        for (int c0 = 0; c0 < SEQ; c0 += 256) {
            #pragma unroll
            for (int rr = 0; rr < 16; ++rr)
                flags[rr][t] = mask[((long)bb * SEQ + R0 + rr) * SEQ + c0 + t] != 0.f;
            __syncthreads();
            unsigned int bits = 0;
            #pragma unroll
            for (int nt = 0; nt < 4; ++nt)
                #pragma unroll
                for (int r = 0; r < 4; ++r)
                    bits |= (unsigned int)flags[ln & 15][tl * 64 + nt * 16 + ((ln >> 4) << 2) + r]
                            << (nt * 4 + r);
            mbits[(((long)bb * 128 + it) * 32 + (c0 >> 6) + tl) * 64 + ln] = (unsigned short)bits;
            __syncthreads();
        }
    }
}

// ---------------------------------------------------------------------------
// GEMM 1 v5 (round-2 verified): 128x128 tile, BK=64, glds16 + 2-phase,
// XOR-swizzled LDS. Grid 24x32 = 768 blocks = 3/CU all-resident.
// ---------------------------------------------------------------------------
__global__ __launch_bounds__(256, 3) void gemm_qkv_f16(
    const unsigned short* __restrict__ Ahg, const unsigned short* __restrict__ Bhg,
    unsigned short* __restrict__ qb, unsigned short* __restrict__ kb,
    unsigned short* __restrict__ vtb) {
    __shared__ __align__(16) unsigned short As[128 * 64];   // 16 KB
    __shared__ __align__(16) unsigned short Bs[128 * 64];   // 16 KB

    const int n0   = blockIdx.x * 128;
    const int m0   = blockIdx.y * 128;
    const int wave = threadIdx.x >> 6;
    const int lane = threadIdx.x & 63;
    const int l16  = lane & 15;
    const int g    = lane >> 4;
    const int wm   = wave & 1;
    const int wn   = wave >> 1;
    const int sw   = l16 & 7;

    const int sr8 = lane >> 3;
    const int scg = (lane & 7) ^ sr8;

    f32x4 acc[4][4] = {};

    for (int k0 = 0; k0 < DIM; k0 += 64) {
        #pragma unroll
        for (int i = 0; i < 4; ++i) {
            const int row = wave * 32 + i * 8;     // wave-uniform; covers 0..127
            glds16(Ahg + (long)(m0 + row + sr8) * DIM + k0 + scg * 8, &As[row * 64]);
            glds16(Bhg + (long)(n0 + row + sr8) * DIM + k0 + scg * 8, &Bs[row * 64]);
        }
        __syncthreads();

        #pragma unroll
        for (int kc = 0; kc < 2; ++kc) {
            half8 a[4], b[4];
            #pragma unroll
            for (int mt = 0; mt < 4; ++mt)
                a[mt] = *reinterpret_cast<const half8*>(
                    &As[(wm * 64 + mt * 16 + l16) * 64 + (((kc * 4 + g) ^ sw) * 8)]);
            #pragma unroll
            for (int nt = 0; nt < 4; ++nt)
                b[nt] = *reinterpret_cast<const half8*>(
                    &Bs[(wn * 64 + nt * 16 + l16) * 64 + (((kc * 4 + g) ^ sw) * 8)]);
            #pragma unroll
            for (int mt = 0; mt < 4; ++mt)
                #pragma unroll
                for (int nt = 0; nt < 4; ++nt)
                    acc[mt][nt] = __builtin_amdgcn_mfma_f32_16x16x32_f16(
                        a[mt], b[nt], acc[mt][nt], 0, 0, 0);
        }
        __syncthreads();
    }

    #pragma unroll
    for (int nt = 0; nt < 4; ++nt) {
        const int n     = n0 + wn * 64 + nt * 16 + l16;
        const int which = n >> 10;                 // block-uniform (1024 % 128 == 0)
        const int rem   = n & 1023;
        const int head  = rem >> 6;
        const int d     = rem & 63;
        #pragma unroll
        for (int mt = 0; mt < 4; ++mt) {
            #pragma unroll
            for (int r = 0; r < 4; ++r) {
                const int m  = m0 + wm * 64 + mt * 16 + g * 4 + r;
                const int bb = m >> 11;
                const int li = m & 2047;
                const int bh_i = bb * HEADS + head;
                const float val = acc[mt][nt][r];
                if (which == 0)
                    qb[((long)bh_i * SEQ + li) * DH + d] = f2h(val * (SCALE * LOG2E));
                else if (which == 1)
                    kb[((long)bh_i * SEQ + li) * DH + d] = f2h(val);
                else
                    vtb[((long)bh_i * DH + d) * SEQ + li] = f2h(val);
            }
        }
    }
}

// ---------------------------------------------------------------------------
// GEMM 2 (round-0 verified): glds16 + __syncthreads, 64x64 tiles, 4/CU.
// ---------------------------------------------------------------------------
__global__ __launch_bounds__(256, 4) void gemm_out_f16(
    const unsigned short* __restrict__ Ahg, const unsigned short* __restrict__ Bhg,
    const float* __restrict__ bias, float* __restrict__ out) {
    __shared__ __align__(16) unsigned short As[64 * 64];
    __shared__ __align__(16) unsigned short Bs[64 * 64];

    const int n0   = blockIdx.x * 64;
    const int m0   = blockIdx.y * 64;
    const int wave = threadIdx.x >> 6;
    const int lane = threadIdx.x & 63;
    const int l16  = lane & 15;
    const int g    = lane >> 4;
    const int wm   = wave & 1;
    const int wn   = wave >> 1;
    const int sw   = l16 & 7;

    const int sr8 = lane >> 3;
    const int scg = (lane & 7) ^ sr8;

    f32x4 acc[2][2] = {};

    for (int k0 = 0; k0 < DIM; k0 += 64) {
        #pragma unroll
        for (int i = 0; i < 2; ++i) {
            const int row = wave * 16 + i * 8;
            glds16(Ahg + (long)(m0 + row + sr8) * DIM + k0 + scg * 8, &As[row * 64]);
            glds16(Bhg + (long)(n0 + row + sr8) * DIM + k0 + scg * 8, &Bs[row * 64]);
        }
        __syncthreads();

        half8 a[2][2];
        #pragma unroll
        for (int mt = 0; mt < 2; ++mt) {
            const int rbase = (wm * 32 + mt * 16 + l16) * 64;
            #pragma unroll
            for (int kc = 0; kc < 2; ++kc)
                a[mt][kc] = *reinterpret_cast<const half8*>(
                    &As[rbase + (((kc * 4 + g) ^ sw) * 8)]);
        }
        #pragma unroll
        for (int nt = 0; nt < 2; ++nt) {
            const int rbase = (wn * 32 + nt * 16 + l16) * 64;
            const half8 b0 = *reinterpret_cast<const half8*>(&Bs[rbase + (((0 + g) ^ sw) * 8)]);
            const half8 b1 = *reinterpret_cast<const half8*>(&Bs[rbase + (((4 + g) ^ sw) * 8)]);
            #pragma unroll
            for (int mt = 0; mt < 2; ++mt) {
                acc[mt][nt] = __builtin_amdgcn_mfma_f32_16x16x32_f16(a[mt][0], b0, acc[mt][nt], 0, 0, 0);
                acc[mt][nt] = __builtin_amdgcn_mfma_f32_16x16x32_f16(a[mt][1], b1, acc[mt][nt], 0, 0, 0);
            }
        }
        __syncthreads();
    }

    #pragma unroll
    for (int nt = 0; nt < 2; ++nt) {
        const int n  = n0 + wn * 32 + nt * 16 + l16;
        const float bv = bias[n];
        #pragma unroll
        for (int mt = 0; mt < 2; ++mt) {
            #pragma unroll
            for (int r = 0; r < 4; ++r) {
                const int m = m0 + wm * 32 + mt * 16 + g * 4 + r;
                out[(long)m * DIM + n] = acc[mt][nt][r] + bv;
            }
        }
    }
}

// ---------------------------------------------------------------------------
// MFMA flash attention v13.1: identical to round-8's v13 (passed correctness)
// with ONE change: __launch_bounds__(512,6) -> (512,4).
// Round-8 post-mortem: the (512,6) bound (85-reg budget, arch-VGPR split=40)
// forced a massive spill (WRITE_SIZE 241 MB, 14 dwords/thread/iter). Every
// (512,4)/(256,4)-bounded build of these same guts measured 64 VGPR, no
// spill. At 64 VGPR the occupancy is LDS-limited: 48 KB x 3 = 144 <= 160 KB
// -> 3 blocks/CU = 6 waves/SIMD (6x64 = 384 <= 512 reg pool). That delivers
// the intended 2->3 blocks/CU occupancy gain over round-4's 61.2 us without
// the spill trigger. XCD-clustered grid keeps staging reads L2-resident
// (verified r5/r6: FETCH collapses to ~ideal).
// ---------------------------------------------------------------------------
__global__ __launch_bounds__(512, 4) void attn_mfma(const unsigned short* __restrict__ qb,
                                                    const unsigned short* __restrict__ kb,
                                                    const unsigned short* __restrict__ vtb,
                                                    const unsigned short* __restrict__ mbits,
                                                    unsigned short* __restrict__ zh) {
    // XCD-clustered decode: flat%8 = XCD; 16 qt-blocks of (bb,h) share an XCD.
    const int flat = blockIdx.x;            // 0..511
    const int xcd  = flat & 7;
    const int rr   = flat >> 3;             // 0..63
    const int hh   = xcd + 8 * (rr >> 4);   // 0..31 packed (bb*16+h)
    const int qt   = rr & 15;               // 128 q-rows each
    const int h    = hh & 15;
    const int bb   = hh >> 4;
    const int bh   = bb * HEADS + h;
    const int wave = threadIdx.x >> 6;      // 0..7
    const int lane = threadIdx.x & 63;
    const int l16  = lane & 15;
    const int g    = lane >> 4;
    const int wm   = wave >> 1;             // row group 0..3 (32 rows each)
    const int wj   = wave & 1;              // j half

    const int myrow0 = qt * 128 + wm * 32;

    // 48 KB: [0,16384) KV shorts (wj*8192 + {K:0,V:4096} + off)
    //        [16384,24576) per-wave P (wave*1024 + off)
    // epilogue reuses [0, 8832 floats) = 35 KB as cmb.
    __shared__ __align__(16) unsigned short shm[24576];
    unsigned short* Ks = &shm[wj * 8192];
    unsigned short* Vs = &shm[wj * 8192 + 4096];
    unsigned short* Pw = &shm[16384 + wave * 1024];

    const int sr8 = lane >> 3;
    const int scg = (lane & 7) ^ sr8;
    const int sw  = l16 & 7;

    const unsigned short* qptr = qb + ((long)bh * SEQ + myrow0 + l16) * DH + g * 8;
    const half8 q0 = *reinterpret_cast<const half8*>(qptr);
    const half8 q1 = *reinterpret_cast<const half8*>(qptr + 32);
    const half8 q2 = *reinterpret_cast<const half8*>(qptr + 16 * DH);
    const half8 q3 = *reinterpret_cast<const half8*>(qptr + 16 * DH + 32);

    half8 ones;
    #pragma unroll
    for (int j = 0; j < 8; ++j) ones[j] = (_Float16)1.0f;

    f32x4 o0[4] = {}, o1[4] = {};
    f32x4 oz0 = {0.f, 0.f, 0.f, 0.f};
    f32x4 oz1 = {0.f, 0.f, 0.f, 0.f};

    const unsigned short* mb =
        mbits + (((long)bb * 128 + qt * 8 + wm * 2) * 32 + wj * 16) * 64 + lane;
    const long kbase = (long)bh * SEQ * DH;
    const long vbase = (long)bh * DH * SEQ;
    const int  jb    = wj * 1024;

    for (int it = 0; it < 16; ++it) {
        const int j0 = jb + it * 64;
        const unsigned int bits0 = mb[(long)it * 64];
        const unsigned int bits1 = mb[(long)it * 64 + 2048];

        // ---- stage K/V tile (per wj half): 4 waves cover rows 0..63 ----
        #pragma unroll
        for (int i = 0; i < 2; ++i) {
            const int row = wm * 16 + i * 8;           // wave-uniform
            glds16(kb  + kbase + (long)(j0 + row + sr8) * DH + scg * 8, Ks + row * 64);
            glds16(vtb + vbase + (long)(row + sr8) * SEQ + j0 + scg * 8, Vs + row * 64);
        }
        __syncthreads();

        // ---- S^T = K Q^T both q-tiles; softmax fused; tile0 P -> LDS,
        //      tile1 P packed in regs ----
        uint2 p1s[4];
        #pragma unroll
        for (int nt = 0; nt < 4; ++nt) {
            const int rbase = (nt * 16 + l16) * 64;
            const half8 k0 = *reinterpret_cast<const half8*>(&Ks[rbase + ((0 + g) ^ sw) * 8]);
            const half8 k1 = *reinterpret_cast<const half8*>(&Ks[rbase + (((4 + g) ^ sw) * 8)]);
            f32x4 s0 = {0.f, 0.f, 0.f, 0.f};
            f32x4 s1 = {0.f, 0.f, 0.f, 0.f};
            s0 = __builtin_amdgcn_mfma_f32_16x16x32_f16(k0, q0, s0, 0, 0, 0);
            s0 = __builtin_amdgcn_mfma_f32_16x16x32_f16(k1, q1, s0, 0, 0, 0);
            s1 = __builtin_amdgcn_mfma_f32_16x16x32_f16(k0, q2, s1, 0, 0, 0);
            s1 = __builtin_amdgcn_mfma_f32_16x16x32_f16(k1, q3, s1, 0, 0, 0);

            float pa[4], pb[4];
            #pragma unroll
            for (int r = 0; r < 4; ++r) {
                const float e0 = __builtin_amdgcn_exp2f(s0[r]);
                const float e1 = __builtin_amdgcn_exp2f(s1[r]);
                pa[r] = ((bits0 >> (nt * 4 + r)) & 1u) ? e0 : 0.f;
                pb[r] = ((bits1 >> (nt * 4 + r)) & 1u) ? e1 : 0.f;
            }
            const int poff = l16 * 64 + (((2 * nt + (g >> 1)) ^ sw) * 8) + (g & 1) * 4;
            uint2 pk0;
            pk0.x = pkrtz(pa[0], pa[1]);
            pk0.y = pkrtz(pa[2], pa[3]);
            *reinterpret_cast<uint2*>(&Pw[poff]) = pk0;
            p1s[nt].x = pkrtz(pb[0], pb[1]);
            p1s[nt].y = pkrtz(pb[2], pb[3]);
        }

        // ---- tile0 P fragments, then overwrite Pw with tile1 (wave-private,
        //      lgkm-ordered: reads complete before aliasing writes) ----
        const half8 pb00 = *reinterpret_cast<const half8*>(&Pw[l16 * 64 + ((0 + g) ^ sw) * 8]);
        const half8 pb01 = *reinterpret_cast<const half8*>(&Pw[l16 * 64 + (((4 + g) ^ sw) * 8)]);
        #pragma unroll
        for (int nt = 0; nt < 4; ++nt) {
            const int poff = l16 * 64 + (((2 * nt + (g >> 1)) ^ sw) * 8) + (g & 1) * 4;
            *reinterpret_cast<uint2*>(&Pw[poff]) = p1s[nt];
        }
        const half8 pb10 = *reinterpret_cast<const half8*>(&Pw[l16 * 64 + ((0 + g) ^ sw) * 8]);
        const half8 pb11 = *reinterpret_cast<const half8*>(&Pw[l16 * 64 + (((4 + g) ^ sw) * 8)]);

        // ---- V fragments once; each feeds both q-tiles' PV ----
        #pragma unroll
        for (int dt = 0; dt < 4; ++dt) {
            const int vb = (dt * 16 + l16) * 64;
            const half8 v0 = *reinterpret_cast<const half8*>(&Vs[vb + ((0 + g) ^ sw) * 8]);
            const half8 v1 = *reinterpret_cast<const half8*>(&Vs[vb + (((4 + g) ^ sw) * 8)]);
            o0[dt] = __builtin_amdgcn_mfma_f32_16x16x32_f16(v0, pb00, o0[dt], 0, 0, 0);
            o0[dt] = __builtin_amdgcn_mfma_f32_16x16x32_f16(v1, pb01, o0[dt], 0, 0, 0);
            o1[dt] = __builtin_amdgcn_mfma_f32_16x16x32_f16(v0, pb10, o1[dt], 0, 0, 0);
            o1[dt] = __builtin_amdgcn_mfma_f32_16x16x32_f16(v1, pb11, o1[dt], 0, 0, 0);
        }
        oz0 = __builtin_amdgcn_mfma_f32_16x16x32_f16(ones, pb00, oz0, 0, 0, 0);
        oz0 = __builtin_amdgcn_mfma_f32_16x16x32_f16(ones, pb01, oz0, 0, 0, 0);
        oz1 = __builtin_amdgcn_mfma_f32_16x16x32_f16(ones, pb10, oz1, 0, 0, 0);
        oz1 = __builtin_amdgcn_mfma_f32_16x16x32_f16(ones, pb11, oz1, 0, 0, 0);
        __syncthreads();    // release KV tile for next staging round
    }

    // ---- combine the two j-halves (linear partials) ----
    float* cmb = (float*)shm;               // 128*68 + 128 floats = 35 KB <= 48 KB
    const int ZOFF = 128 * 68;
    const int ci0  = wm * 32 + l16;
    const int ci1  = ci0 + 16;
    if (wj == 1) {
        #pragma unroll
        for (int dt = 0; dt < 4; ++dt) {
            *reinterpret_cast<f32x4*>(&cmb[ci0 * 68 + dt * 16 + g * 4]) = o0[dt];
            *reinterpret_cast<f32x4*>(&cmb[ci1 * 68 + dt * 16 + g * 4]) = o1[dt];
        }
        if (g == 0) {
            cmb[ZOFF + ci0] = oz0[0];
            cmb[ZOFF + ci1] = oz1[0];
        }
    }
    __syncthreads();
    if (wj == 0) {
        const float Z0   = oz0[0] + cmb[ZOFF + ci0];
        const float Z1   = oz1[0] + cmb[ZOFF + ci1];
        const float inv0 = 1.f / (Z0 + 1e-30f);
        const float inv1 = 1.f / (Z1 + 1e-30f);
        const long obase0 = ((long)bb * SEQ + myrow0 + l16) * DIM + h * DH;
        const long obase1 = obase0 + (long)16 * DIM;
        #pragma unroll
        for (int dt = 0; dt < 4; ++dt) {
            const f32x4 oc0 = *reinterpret_cast<const f32x4*>(&cmb[ci0 * 68 + dt * 16 + g * 4]);
            const f32x4 oc1 = *reinterpret_cast<const f32x4*>(&cmb[ci1 * 68 + dt * 16 + g * 4]);
            uint2 pk;
            pk.x = pkrtz((o0[dt][0] + oc0[0]) * inv0, (o0[dt][1] + oc0[1]) * inv0);
            pk.y = pkrtz((o0[dt][2] + oc0[2]) * inv0, (o0[dt][3] + oc0[3]) * inv0);
            *reinterpret_cast<uint2*>(zh + obase0 + dt * 16 + g * 4) = pk;
            pk.x = pkrtz((o1[dt][0] + oc1[0]) * inv1, (o1[dt][1] + oc1[1]) * inv1);
            pk.y = pkrtz((o1[dt][2] + oc1[2]) * inv1, (o1[dt][3] + oc1[3]) * inv1);
            *reinterpret_cast<uint2*>(zh + obase1 + dt * 16 + g * 4) = pk;
        }
    }
}

// ---------------------------------------------------------------------------
extern "C" void kernel_launch(void* const* d_in, const int* in_sizes, int n_in,
                              void* d_out, int out_size, void* d_ws, size_t ws_size,
                              hipStream_t stream) {
    const float* x     = (const float*)d_in[0];
    const float* mask  = (const float*)d_in[1];
    const float* W_qkv = (const float*)d_in[2];
    const float* W_out = (const float*)d_in[3];
    const float* b_out = (const float*)d_in[4];
    float* out = (float*)d_out;

    unsigned short* ws = (unsigned short*)d_ws;
    unsigned short* xh    = ws;                  // 4M fp16 (reused as z after gemm1)
    unsigned short* WqT   = xh    + 4194304;     // 3M fp16
    unsigned short* WoT   = WqT   + 3145728;     // 1M fp16
    unsigned short* qbu   = WoT   + 1048576;     // 4M fp16
    unsigned short* kbu   = qbu   + 4194304;     // 4M fp16
    unsigned short* vtb   = kbu   + 4194304;     // 4M fp16
    unsigned short* mbits = vtb   + 4194304;     // 0.5M -> 41 MB total
    unsigned short* zz    = xh;

    prepass<<<8448, 256, 0, stream>>>(x, xh, W_qkv, WqT, W_out, WoT, mask, mbits);

    gemm_qkv_f16<<<dim3(24, 32), 256, 0, stream>>>(xh, WqT, qbu, kbu, vtb);

    attn_mfma<<<512, 512, 0, stream>>>(qbu, kbu, vtb, mbits, zz);

    gemm_out_f16<<<dim3(16, 64), 256, 0, stream>>>(zz, WoT, b_out, out);
}

// Round 10
// 232.934 us; speedup vs baseline: 1.3570x; 1.0000x over previous
//
#include <hip/hip_runtime.h>
#include <hip/hip_bf16.h>

// x: [2, 2048, 1024] f32; mask: [2, 2048, 2048] f32; W_qkv: [1024, 3072] f32
// W_out: [1024, 1024] f32; b_out: [1024] f32; out: [2, 2048, 1024] f32
#define BATCH 2
#define SEQ   2048
#define DIM   1024
#define HEADS 16
#define DH    64
#define N_QKV 3072
#define M_TOT 4096
#define SCALE 0.125f
#define EPS   1e-10f
#define LOG2E 1.442695041f

typedef __attribute__((ext_vector_type(8))) _Float16 half8;
typedef __attribute__((ext_vector_type(4))) float f32x4;

static __device__ __forceinline__ unsigned short f2h(float f) {
    _Float16 h = (_Float16)f;
    return __builtin_bit_cast(unsigned short, h);
}
static __device__ __forceinline__ unsigned int pkrtz(float a, float b) {
#if defined(__has_builtin) && __has_builtin(__builtin_amdgcn_cvt_pkrtz)
    return __builtin_bit_cast(unsigned int, __builtin_amdgcn_cvt_pkrtz(a, b));
#else
    return (unsigned int)f2h(a) | ((unsigned int)f2h(b) << 16);
#endif
}
static __device__ __forceinline__ void glds16(const void* g, void* l) {
    __builtin_amdgcn_global_load_lds((const __attribute__((address_space(1))) void*)g,
                                     (__attribute__((address_space(3))) void*)l,
                                     16, 0, 0);
}

// ---------------------------------------------------------------------------
// Merged pre-pass (r15): one launch, 4 independent jobs by block range.
// ---------------------------------------------------------------------------
__global__ __launch_bounds__(256) void prepass(const float* __restrict__ x,
                                               unsigned short* __restrict__ xh,
                                               const float* __restrict__ Wq,
                                               unsigned short* __restrict__ WqT,
                                               const float* __restrict__ Wo,
                                               unsigned short* __restrict__ WoT,
                                               const float* __restrict__ mask,
                                               unsigned short* __restrict__ mbits) {
    const int bid = blockIdx.x;
    const int t   = threadIdx.x;
    __shared__ float tile[32][33];
    __shared__ unsigned char flags[16][256];

    if (bid < 4096) {
        const int i = bid * 256 + t;
        float4 v = reinterpret_cast<const float4*>(x)[i];
        uint2 o;
        o.x = pkrtz(v.x, v.y);
        o.y = pkrtz(v.z, v.w);
        reinterpret_cast<uint2*>(xh)[i] = o;
    } else if (bid < 8192) {
        const float* src; unsigned short* th; int rows, cols, bx;
        if (bid < 7168) { src = Wq; th = WqT; rows = 1024; cols = 3072; bx = bid - 4096;
        } else          { src = Wo; th = WoT; rows = 1024; cols = 1024; bx = bid - 7168; }
        const int nbx = cols / 32;
        const int c0 = (bx % nbx) * 32, r0 = (bx / nbx) * 32;
        const int tx = t & 31, ty = t >> 5;
        #pragma unroll
        for (int i = ty; i < 32; i += 8)
            tile[i][tx] = src[(long)(r0 + i) * cols + c0 + tx];
        __syncthreads();
        #pragma unroll
        for (int i = ty; i < 32; i += 8)
            th[(long)(c0 + i) * rows + r0 + tx] = f2h(tile[tx][i]);
    } else {
        const int bx = bid - 8192;
        const int it = bx & 127;
        const int bb = bx >> 7;
        const int R0 = it * 16;
        const int tl = t >> 6, ln = t & 63;
        for (int c0 = 0; c0 < SEQ; c0 += 256) {
            #pragma unroll
            for (int rr = 0; rr < 16; ++rr)
                flags[rr][t] = mask[((long)bb * SEQ + R0 + rr) * SEQ + c0 + t] != 0.f;
            __syncthreads();
            unsigned int bits = 0;
            #pragma unroll
            for (int nt = 0; nt < 4; ++nt)
                #pragma unroll
                for (int r = 0; r < 4; ++r)
                    bits |= (unsigned int)flags[ln & 15][tl * 64 + nt * 16 + ((ln >> 4) << 2) + r]
                            << (nt * 4 + r);
            mbits[(((long)bb * 128 + it) * 32 + (c0 >> 6) + tl) * 64 + ln] = (unsigned short)bits;
            __syncthreads();
        }
    }
}

// ---------------------------------------------------------------------------
// GEMM 1 v5 (round-2 verified): 128x128 tile, BK=64, glds16 + 2-phase,
// XOR-swizzled LDS. Grid 24x32 = 768 blocks = 3/CU all-resident.
// ---------------------------------------------------------------------------
__global__ __launch_bounds__(256, 3) void gemm_qkv_f16(
    const unsigned short* __restrict__ Ahg, const unsigned short* __restrict__ Bhg,
    unsigned short* __restrict__ qb, unsigned short* __restrict__ kb,
    unsigned short* __restrict__ vtb) {
    __shared__ __align__(16) unsigned short As[128 * 64];   // 16 KB
    __shared__ __align__(16) unsigned short Bs[128 * 64];   // 16 KB

    const int n0   = blockIdx.x * 128;
    const int m0   = blockIdx.y * 128;
    const int wave = threadIdx.x >> 6;
    const int lane = threadIdx.x & 63;
    const int l16  = lane & 15;
    const int g    = lane >> 4;
    const int wm   = wave & 1;
    const int wn   = wave >> 1;
    const int sw   = l16 & 7;

    const int sr8 = lane >> 3;
    const int scg = (lane & 7) ^ sr8;

    f32x4 acc[4][4] = {};

    for (int k0 = 0; k0 < DIM; k0 += 64) {
        #pragma unroll
        for (int i = 0; i < 4; ++i) {
            const int row = wave * 32 + i * 8;     // wave-uniform; covers 0..127
            glds16(Ahg + (long)(m0 + row + sr8) * DIM + k0 + scg * 8, &As[row * 64]);
            glds16(Bhg + (long)(n0 + row + sr8) * DIM + k0 + scg * 8, &Bs[row * 64]);
        }
        __syncthreads();

        #pragma unroll
        for (int kc = 0; kc < 2; ++kc) {
            half8 a[4], b[4];
            #pragma unroll
            for (int mt = 0; mt < 4; ++mt)
                a[mt] = *reinterpret_cast<const half8*>(
                    &As[(wm * 64 + mt * 16 + l16) * 64 + (((kc * 4 + g) ^ sw) * 8)]);
            #pragma unroll
            for (int nt = 0; nt < 4; ++nt)
                b[nt] = *reinterpret_cast<const half8*>(
                    &Bs[(wn * 64 + nt * 16 + l16) * 64 + (((kc * 4 + g) ^ sw) * 8)]);
            #pragma unroll
            for (int mt = 0; mt < 4; ++mt)
                #pragma unroll
                for (int nt = 0; nt < 4; ++nt)
                    acc[mt][nt] = __builtin_amdgcn_mfma_f32_16x16x32_f16(
                        a[mt], b[nt], acc[mt][nt], 0, 0, 0);
        }
        __syncthreads();
    }

    #pragma unroll
    for (int nt = 0; nt < 4; ++nt) {
        const int n     = n0 + wn * 64 + nt * 16 + l16;
        const int which = n >> 10;                 // block-uniform (1024 % 128 == 0)
        const int rem   = n & 1023;
        const int head  = rem >> 6;
        const int d     = rem & 63;
        #pragma unroll
        for (int mt = 0; mt < 4; ++mt) {
            #pragma unroll
            for (int r = 0; r < 4; ++r) {
                const int m  = m0 + wm * 64 + mt * 16 + g * 4 + r;
                const int bb = m >> 11;
                const int li = m & 2047;
                const int bh_i = bb * HEADS + head;
                const float val = acc[mt][nt][r];
                if (which == 0)
                    qb[((long)bh_i * SEQ + li) * DH + d] = f2h(val * (SCALE * LOG2E));
                else if (which == 1)
                    kb[((long)bh_i * SEQ + li) * DH + d] = f2h(val);
                else
                    vtb[((long)bh_i * DH + d) * SEQ + li] = f2h(val);
            }
        }
    }
}

// ---------------------------------------------------------------------------
// GEMM 2 (round-0 verified): glds16 + __syncthreads, 64x64 tiles, 4/CU.
// ---------------------------------------------------------------------------
__global__ __launch_bounds__(256, 4) void gemm_out_f16(
    const unsigned short* __restrict__ Ahg, const unsigned short* __restrict__ Bhg,
    const float* __restrict__ bias, float* __restrict__ out) {
    __shared__ __align__(16) unsigned short As[64 * 64];
    __shared__ __align__(16) unsigned short Bs[64 * 64];

    const int n0   = blockIdx.x * 64;
    const int m0   = blockIdx.y * 64;
    const int wave = threadIdx.x >> 6;
    const int lane = threadIdx.x & 63;
    const int l16  = lane & 15;
    const int g    = lane >> 4;
    const int wm   = wave & 1;
    const int wn   = wave >> 1;
    const int sw   = l16 & 7;

    const int sr8 = lane >> 3;
    const int scg = (lane & 7) ^ sr8;

    f32x4 acc[2][2] = {};

    for (int k0 = 0; k0 < DIM; k0 += 64) {
        #pragma unroll
        for (int i = 0; i < 2; ++i) {
            const int row = wave * 16 + i * 8;
            glds16(Ahg + (long)(m0 + row + sr8) * DIM + k0 + scg * 8, &As[row * 64]);
            glds16(Bhg + (long)(n0 + row + sr8) * DIM + k0 + scg * 8, &Bs[row * 64]);
        }
        __syncthreads();

        half8 a[2][2];
        #pragma unroll
        for (int mt = 0; mt < 2; ++mt) {
            const int rbase = (wm * 32 + mt * 16 + l16) * 64;
            #pragma unroll
            for (int kc = 0; kc < 2; ++kc)
                a[mt][kc] = *reinterpret_cast<const half8*>(
                    &As[rbase + (((kc * 4 + g) ^ sw) * 8)]);
        }
        #pragma unroll
        for (int nt = 0; nt < 2; ++nt) {
            const int rbase = (wn * 32 + nt * 16 + l16) * 64;
            const half8 b0 = *reinterpret_cast<const half8*>(&Bs[rbase + (((0 + g) ^ sw) * 8)]);
            const half8 b1 = *reinterpret_cast<const half8*>(&Bs[rbase + (((4 + g) ^ sw) * 8)]);
            #pragma unroll
            for (int mt = 0; mt < 2; ++mt) {
                acc[mt][nt] = __builtin_amdgcn_mfma_f32_16x16x32_f16(a[mt][0], b0, acc[mt][nt], 0, 0, 0);
                acc[mt][nt] = __builtin_amdgcn_mfma_f32_16x16x32_f16(a[mt][1], b1, acc[mt][nt], 0, 0, 0);
            }
        }
        __syncthreads();
    }

    #pragma unroll
    for (int nt = 0; nt < 2; ++nt) {
        const int n  = n0 + wn * 32 + nt * 16 + l16;
        const float bv = bias[n];
        #pragma unroll
        for (int mt = 0; mt < 2; ++mt) {
            #pragma unroll
            for (int r = 0; r < 4; ++r) {
                const int m = m0 + wm * 32 + mt * 16 + g * 4 + r;
                out[(long)m * DIM + n] = acc[mt][nt][r] + bv;
            }
        }
    }
}

// ---------------------------------------------------------------------------
// MFMA flash attention v14 (this round): r9's v13.1 (61.6 us, no spill) with
// two dependency-chain edits, all else identical:
//  1. V fragments hoisted to registers, read interleaved per-nt inside the
//     QK loop — their LDS latency drains under the softmax VALU instead of
//     serializing after the P round-trip (compiler can't hoist them itself:
//     Pw/Vs LDS disjointness isn't provable). PV consumes regs only.
//     +32 VGPR (vr[4][2]) -> ~96, under the (512,4)=128 cap.
//  2. T5 s_setprio(1/0) around the QK MFMA quads and the PV MFMA cluster
//     (m191: +4-7% attn with phase-diverse waves; 2 independent blocks/CU).
// Spill sentinel: WRITE_SIZE must stay ~8 MB (r8 lesson: spill => 241 MB).
// ---------------------------------------------------------------------------
__global__ __launch_bounds__(512, 4) void attn_mfma(const unsigned short* __restrict__ qb,
                                                    const unsigned short* __restrict__ kb,
                                                    const unsigned short* __restrict__ vtb,
                                                    const unsigned short* __restrict__ mbits,
                                                    unsigned short* __restrict__ zh) {
    // XCD-clustered decode: flat%8 = XCD; 16 qt-blocks of (bb,h) share an XCD.
    const int flat = blockIdx.x;            // 0..511
    const int xcd  = flat & 7;
    const int rr   = flat >> 3;             // 0..63
    const int hh   = xcd + 8 * (rr >> 4);   // 0..31 packed (bb*16+h)
    const int qt   = rr & 15;               // 128 q-rows each
    const int h    = hh & 15;
    const int bb   = hh >> 4;
    const int bh   = bb * HEADS + h;
    const int wave = threadIdx.x >> 6;      // 0..7
    const int lane = threadIdx.x & 63;
    const int l16  = lane & 15;
    const int g    = lane >> 4;
    const int wm   = wave >> 1;             // row group 0..3 (32 rows each)
    const int wj   = wave & 1;              // j half

    const int myrow0 = qt * 128 + wm * 32;

    // 48 KB: [0,16384) KV shorts (wj*8192 + {K:0,V:4096} + off)
    //        [16384,24576) per-wave P (wave*1024 + off)
    // epilogue reuses [0, 8832 floats) = 35 KB as cmb.
    __shared__ __align__(16) unsigned short shm[24576];
    unsigned short* Ks = &shm[wj * 8192];
    unsigned short* Vs = &shm[wj * 8192 + 4096];
    unsigned short* Pw = &shm[16384 + wave * 1024];

    const int sr8 = lane >> 3;
    const int scg = (lane & 7) ^ sr8;
    const int sw  = l16 & 7;

    const unsigned short* qptr = qb + ((long)bh * SEQ + myrow0 + l16) * DH + g * 8;
    const half8 q0 = *reinterpret_cast<const half8*>(qptr);
    const half8 q1 = *reinterpret_cast<const half8*>(qptr + 32);
    const half8 q2 = *reinterpret_cast<const half8*>(qptr + 16 * DH);
    const half8 q3 = *reinterpret_cast<const half8*>(qptr + 16 * DH + 32);

    half8 ones;
    #pragma unroll
    for (int j = 0; j < 8; ++j) ones[j] = (_Float16)1.0f;

    f32x4 o0[4] = {}, o1[4] = {};
    f32x4 oz0 = {0.f, 0.f, 0.f, 0.f};
    f32x4 oz1 = {0.f, 0.f, 0.f, 0.f};

    const unsigned short* mb =
        mbits + (((long)bb * 128 + qt * 8 + wm * 2) * 32 + wj * 16) * 64 + lane;
    const long kbase = (long)bh * SEQ * DH;
    const long vbase = (long)bh * DH * SEQ;
    const int  jb    = wj * 1024;

    for (int it = 0; it < 16; ++it) {
        const int j0 = jb + it * 64;
        const unsigned int bits0 = mb[(long)it * 64];
        const unsigned int bits1 = mb[(long)it * 64 + 2048];

        // ---- stage K/V tile (per wj half): 4 waves cover rows 0..63 ----
        #pragma unroll
        for (int i = 0; i < 2; ++i) {
            const int row = wm * 16 + i * 8;           // wave-uniform
            glds16(kb  + kbase + (long)(j0 + row + sr8) * DH + scg * 8, Ks + row * 64);
            glds16(vtb + vbase + (long)(row + sr8) * SEQ + j0 + scg * 8, Vs + row * 64);
        }
        __syncthreads();

        // ---- S^T = K Q^T both q-tiles; V reads interleaved (independent of
        //      softmax, latency hides under the VALU); tile0 P -> LDS,
        //      tile1 P packed in regs ----
        half8 vr0[4], vr1[4];
        uint2 p1s[4];
        #pragma unroll
        for (int nt = 0; nt < 4; ++nt) {
            const int rbase = (nt * 16 + l16) * 64;
            const half8 k0 = *reinterpret_cast<const half8*>(&Ks[rbase + ((0 + g) ^ sw) * 8]);
            const half8 k1 = *reinterpret_cast<const half8*>(&Ks[rbase + (((4 + g) ^ sw) * 8)]);
            f32x4 s0 = {0.f, 0.f, 0.f, 0.f};
            f32x4 s1 = {0.f, 0.f, 0.f, 0.f};
            __builtin_amdgcn_s_setprio(1);
            s0 = __builtin_amdgcn_mfma_f32_16x16x32_f16(k0, q0, s0, 0, 0, 0);
            s0 = __builtin_amdgcn_mfma_f32_16x16x32_f16(k1, q1, s0, 0, 0, 0);
            s1 = __builtin_amdgcn_mfma_f32_16x16x32_f16(k0, q2, s1, 0, 0, 0);
            s1 = __builtin_amdgcn_mfma_f32_16x16x32_f16(k1, q3, s1, 0, 0, 0);
            __builtin_amdgcn_s_setprio(0);

            // V fragment pair for dt=nt: issues now, drains under softmax
            const int vb = rbase;                      // same (nt*16+l16)*64
            vr0[nt] = *reinterpret_cast<const half8*>(&Vs[vb + ((0 + g) ^ sw) * 8]);
            vr1[nt] = *reinterpret_cast<const half8*>(&Vs[vb + (((4 + g) ^ sw) * 8)]);

            float pa[4], pb[4];
            #pragma unroll
            for (int r = 0; r < 4; ++r) {
                const float e0 = __builtin_amdgcn_exp2f(s0[r]);
                const float e1 = __builtin_amdgcn_exp2f(s1[r]);
                pa[r] = ((bits0 >> (nt * 4 + r)) & 1u) ? e0 : 0.f;
                pb[r] = ((bits1 >> (nt * 4 + r)) & 1u) ? e1 : 0.f;
            }
            const int poff = l16 * 64 + (((2 * nt + (g >> 1)) ^ sw) * 8) + (g & 1) * 4;
            uint2 pk0;
            pk0.x = pkrtz(pa[0], pa[1]);
            pk0.y = pkrtz(pa[2], pa[3]);
            *reinterpret_cast<uint2*>(&Pw[poff]) = pk0;
            p1s[nt].x = pkrtz(pb[0], pb[1]);
            p1s[nt].y = pkrtz(pb[2], pb[3]);
        }

        // ---- tile0 P fragments, then overwrite Pw with tile1 (wave-private,
        //      lgkm-ordered: reads complete before aliasing writes) ----
        const half8 pb00 = *reinterpret_cast<const half8*>(&Pw[l16 * 64 + ((0 + g) ^ sw) * 8]);
        const half8 pb01 = *reinterpret_cast<const half8*>(&Pw[l16 * 64 + (((4 + g) ^ sw) * 8)]);
        #pragma unroll
        for (int nt = 0; nt < 4; ++nt) {
            const int poff = l16 * 64 + (((2 * nt + (g >> 1)) ^ sw) * 8) + (g & 1) * 4;
            *reinterpret_cast<uint2*>(&Pw[poff]) = p1s[nt];
        }
        const half8 pb10 = *reinterpret_cast<const half8*>(&Pw[l16 * 64 + ((0 + g) ^ sw) * 8]);
        const half8 pb11 = *reinterpret_cast<const half8*>(&Pw[l16 * 64 + (((4 + g) ^ sw) * 8)]);

        // ---- O^T += V^T P^T from registers; pure-MFMA region ----
        __builtin_amdgcn_s_setprio(1);
        #pragma unroll
        for (int dt = 0; dt < 4; ++dt) {
            o0[dt] = __builtin_amdgcn_mfma_f32_16x16x32_f16(vr0[dt], pb00, o0[dt], 0, 0, 0);
            o0[dt] = __builtin_amdgcn_mfma_f32_16x16x32_f16(vr1[dt], pb01, o0[dt], 0, 0, 0);
            o1[dt] = __builtin_amdgcn_mfma_f32_16x16x32_f16(vr0[dt], pb10, o1[dt], 0, 0, 0);
            o1[dt] = __builtin_amdgcn_mfma_f32_16x16x32_f16(vr1[dt], pb11, o1[dt], 0, 0, 0);
        }
        oz0 = __builtin_amdgcn_mfma_f32_16x16x32_f16(ones, pb00, oz0, 0, 0, 0);
        oz0 = __builtin_amdgcn_mfma_f32_16x16x32_f16(ones, pb01, oz0, 0, 0, 0);
        oz1 = __builtin_amdgcn_mfma_f32_16x16x32_f16(ones, pb10, oz1, 0, 0, 0);
        oz1 = __builtin_amdgcn_mfma_f32_16x16x32_f16(ones, pb11, oz1, 0, 0, 0);
        __builtin_amdgcn_s_setprio(0);
        __syncthreads();    // release KV tile for next staging round
    }

    // ---- combine the two j-halves (linear partials) ----
    float* cmb = (float*)shm;               // 128*68 + 128 floats = 35 KB <= 48 KB
    const int ZOFF = 128 * 68;
    const int ci0  = wm * 32 + l16;
    const int ci1  = ci0 + 16;
    if (wj == 1) {
        #pragma unroll
        for (int dt = 0; dt < 4; ++dt) {
            *reinterpret_cast<f32x4*>(&cmb[ci0 * 68 + dt * 16 + g * 4]) = o0[dt];
            *reinterpret_cast<f32x4*>(&cmb[ci1 * 68 + dt * 16 + g * 4]) = o1[dt];
        }
        if (g == 0) {
            cmb[ZOFF + ci0] = oz0[0];
            cmb[ZOFF + ci1] = oz1[0];
        }
    }
    __syncthreads();
    if (wj == 0) {
        const float Z0   = oz0[0] + cmb[ZOFF + ci0];
        const float Z1   = oz1[0] + cmb[ZOFF + ci1];
        const float inv0 = 1.f / (Z0 + 1e-30f);
        const float inv1 = 1.f / (Z1 + 1e-30f);
        const long obase0 = ((long)bb * SEQ + myrow0 + l16) * DIM + h * DH;
        const long obase1 = obase0 + (long)16 * DIM;
        #pragma unroll
        for (int dt = 0; dt < 4; ++dt) {
            const f32x4 oc0 = *reinterpret_cast<const f32x4*>(&cmb[ci0 * 68 + dt * 16 + g * 4]);
            const f32x4 oc1 = *reinterpret_cast<const f32x4*>(&cmb[ci1 * 68 + dt * 16 + g * 4]);
            uint2 pk;
            pk.x = pkrtz((o0[dt][0] + oc0[0]) * inv0, (o0[dt][1] + oc0[1]) * inv0);
            pk.y = pkrtz((o0[dt][2] + oc0[2]) * inv0, (o0[dt][3] + oc0[3]) * inv0);
            *reinterpret_cast<uint2*>(zh + obase0 + dt * 16 + g * 4) = pk;
            pk.x = pkrtz((o1[dt][0] + oc1[0]) * inv1, (o1[dt][1] + oc1[1]) * inv1);
            pk.y = pkrtz((o1[dt][2] + oc1[2]) * inv1, (o1[dt][3] + oc1[3]) * inv1);
            *reinterpret_cast<uint2*>(zh + obase1 + dt * 16 + g * 4) = pk;
        }
    }
}

// ---------------------------------------------------------------------------
extern "C" void kernel_launch(void* const* d_in, const int* in_sizes, int n_in,
                              void* d_out, int out_size, void* d_ws, size_t ws_size,
                              hipStream_t stream) {
    const float* x     = (const float*)d_in[0];
    const float* mask  = (const float*)d_in[1];
    const float* W_qkv = (const float*)d_in[2];
    const float* W_out = (const float*)d_in[3];
    const float* b_out = (const float*)d_in[4];
    float* out = (float*)d_out;

    unsigned short* ws = (unsigned short*)d_ws;
    unsigned short* xh    = ws;                  // 4M fp16 (reused as z after gemm1)
    unsigned short* WqT   = xh    + 4194304;     // 3M fp16
    unsigned short* WoT   = WqT   + 3145728;     // 1M fp16
    unsigned short* qbu   = WoT   + 1048576;     // 4M fp16
    unsigned short* kbu   = qbu   + 4194304;     // 4M fp16
    unsigned short* vtb   = kbu   + 4194304;     // 4M fp16
    unsigned short* mbits = vtb   + 4194304;     // 0.5M -> 41 MB total
    unsigned short* zz    = xh;

    prepass<<<8448, 256, 0, stream>>>(x, xh, W_qkv, WqT, W_out, WoT, mask, mbits);

    gemm_qkv_f16<<<dim3(24, 32), 256, 0, stream>>>(xh, WqT, qbu, kbu, vtb);

    attn_mfma<<<512, 512, 0, stream>>>(qbu, kbu, vtb, mbits, zz);

    gemm_out_f16<<<dim3(16, 64), 256, 0, stream>>>(zz, WoT, b_out, out);
}

// Round 11
// 221.855 us; speedup vs baseline: 1.4248x; 1.0499x over previous
//
#include <hip/hip_runtime.h>
#include <hip/hip_bf16.h>

// x: [2, 2048, 1024] f32; mask: [2, 2048, 2048] f32; W_qkv: [1024, 3072] f32
// W_out: [1024, 1024] f32; b_out: [1024] f32; out: [2, 2048, 1024] f32
#define BATCH 2
#define SEQ   2048
#define DIM   1024
#define HEADS 16
#define DH    64
#define N_QKV 3072
#define M_TOT 4096
#define SCALE 0.125f
#define EPS   1e-10f
#define LOG2E 1.442695041f

typedef __attribute__((ext_vector_type(8))) _Float16 half8;
typedef __attribute__((ext_vector_type(4))) float f32x4;

static __device__ __forceinline__ unsigned short f2h(float f) {
    _Float16 h = (_Float16)f;
    return __builtin_bit_cast(unsigned short, h);
}
static __device__ __forceinline__ unsigned int pkrtz(float a, float b) {
#if defined(__has_builtin) && __has_builtin(__builtin_amdgcn_cvt_pkrtz)
    return __builtin_bit_cast(unsigned int, __builtin_amdgcn_cvt_pkrtz(a, b));
#else
    return (unsigned int)f2h(a) | ((unsigned int)f2h(b) << 16);
#endif
}
static __device__ __forceinline__ void glds16(const void* g, void* l) {
    __builtin_amdgcn_global_load_lds((const __attribute__((address_space(1))) void*)g,
                                     (__attribute__((address_space(3))) void*)l,
                                     16, 0, 0);
}

// ---------------------------------------------------------------------------
// Merged pre-pass (r15): one launch, 4 independent jobs by block range.
// ---------------------------------------------------------------------------
__global__ __launch_bounds__(256) void prepass(const float* __restrict__ x,
                                               unsigned short* __restrict__ xh,
                                               const float* __restrict__ Wq,
                                               unsigned short* __restrict__ WqT,
                                               const float* __restrict__ Wo,
                                               unsigned short* __restrict__ WoT,
                                               const float* __restrict__ mask,
                                               unsigned short* __restrict__ mbits) {
    const int bid = blockIdx.x;
    const int t   = threadIdx.x;
    __shared__ float tile[32][33];
    __shared__ unsigned char flags[16][256];

    if (bid < 4096) {
        const int i = bid * 256 + t;
        float4 v = reinterpret_cast<const float4*>(x)[i];
        uint2 o;
        o.x = pkrtz(v.x, v.y);
        o.y = pkrtz(v.z, v.w);
        reinterpret_cast<uint2*>(xh)[i] = o;
    } else if (bid < 8192) {
        const float* src; unsigned short* th; int rows, cols, bx;
        if (bid < 7168) { src = Wq; th = WqT; rows = 1024; cols = 3072; bx = bid - 4096;
        } else          { src = Wo; th = WoT; rows = 1024; cols = 1024; bx = bid - 7168; }
        const int nbx = cols / 32;
        const int c0 = (bx % nbx) * 32, r0 = (bx / nbx) * 32;
        const int tx = t & 31, ty = t >> 5;
        #pragma unroll
        for (int i = ty; i < 32; i += 8)
            tile[i][tx] = src[(long)(r0 + i) * cols + c0 + tx];
        __syncthreads();
        #pragma unroll
        for (int i = ty; i < 32; i += 8)
            th[(long)(c0 + i) * rows + r0 + tx] = f2h(tile[tx][i]);
    } else {
        const int bx = bid - 8192;
        const int it = bx & 127;
        const int bb = bx >> 7;
        const int R0 = it * 16;
        const int tl = t >> 6, ln = t & 63;
        for (int c0 = 0; c0 < SEQ; c0 += 256) {
            #pragma unroll
            for (int rr = 0; rr < 16; ++rr)
                flags[rr][t] = mask[((long)bb * SEQ + R0 + rr) * SEQ + c0 + t] != 0.f;
            __syncthreads();
            unsigned int bits = 0;
            #pragma unroll
            for (int nt = 0; nt < 4; ++nt)
                #pragma unroll
                for (int r = 0; r < 4; ++r)
                    bits |= (unsigned int)flags[ln & 15][tl * 64 + nt * 16 + ((ln >> 4) << 2) + r]
                            << (nt * 4 + r);
            mbits[(((long)bb * 128 + it) * 32 + (c0 >> 6) + tl) * 64 + ln] = (unsigned short)bits;
            __syncthreads();
        }
    }
}

// ---------------------------------------------------------------------------
// GEMM 1 v6 (this round): round-2-verified 128x128/BK=64/glds16 compute with
// two epilogue/dispatch edits:
//  (a) XCD-tile swizzle (T1): 768 blocks -> 8 rectangles of 8m x 12n.
//      Default dispatch re-fetched the whole A matrix on all 8 XCD L2s
//      (~73 MB); rectangles cut panel fetch to ~42 MB and make staging
//      reads L2-local.
//  (b) vtb (V^T) store packing: r-run (r=0..3) is contiguous in li ->
//      one uint2 (8 B) store instead of 4 scalar 2 B stores. Fixes the
//      worst write-scatter (16.8 MB at 2 B granularity, 4 KB apart).
// ---------------------------------------------------------------------------
__global__ __launch_bounds__(256, 3) void gemm_qkv_f16(
    const unsigned short* __restrict__ Ahg, const unsigned short* __restrict__ Bhg,
    unsigned short* __restrict__ qb, unsigned short* __restrict__ kb,
    unsigned short* __restrict__ vtb) {
    __shared__ __align__(16) unsigned short As[128 * 64];   // 16 KB
    __shared__ __align__(16) unsigned short Bs[128 * 64];   // 16 KB

    // XCD-tile decode: f%8 = XCD (round-robin dispatch); each XCD owns an
    // 8m x 12n rectangle of the 32x24 block grid. Bijective: 8*96 = 768.
    const int f   = blockIdx.x;
    const int xcd = f & 7;
    const int c   = f >> 3;              // 0..95 within-XCD
    const int rm  = xcd & 3;             // 4 rect-rows
    const int rn  = xcd >> 2;            // 2 rect-cols
    const int by  = rm * 8 + c / 12;     // 0..31
    const int bx  = rn * 12 + c % 12;    // 0..23
    const int n0  = bx * 128;
    const int m0  = by * 128;

    const int wave = threadIdx.x >> 6;
    const int lane = threadIdx.x & 63;
    const int l16  = lane & 15;
    const int g    = lane >> 4;
    const int wm   = wave & 1;
    const int wn   = wave >> 1;
    const int sw   = l16 & 7;

    const int sr8 = lane >> 3;
    const int scg = (lane & 7) ^ sr8;

    f32x4 acc[4][4] = {};

    for (int k0 = 0; k0 < DIM; k0 += 64) {
        #pragma unroll
        for (int i = 0; i < 4; ++i) {
            const int row = wave * 32 + i * 8;     // wave-uniform; covers 0..127
            glds16(Ahg + (long)(m0 + row + sr8) * DIM + k0 + scg * 8, &As[row * 64]);
            glds16(Bhg + (long)(n0 + row + sr8) * DIM + k0 + scg * 8, &Bs[row * 64]);
        }
        __syncthreads();

        #pragma unroll
        for (int kc = 0; kc < 2; ++kc) {
            half8 a[4], b[4];
            #pragma unroll
            for (int mt = 0; mt < 4; ++mt)
                a[mt] = *reinterpret_cast<const half8*>(
                    &As[(wm * 64 + mt * 16 + l16) * 64 + (((kc * 4 + g) ^ sw) * 8)]);
            #pragma unroll
            for (int nt = 0; nt < 4; ++nt)
                b[nt] = *reinterpret_cast<const half8*>(
                    &Bs[(wn * 64 + nt * 16 + l16) * 64 + (((kc * 4 + g) ^ sw) * 8)]);
            #pragma unroll
            for (int mt = 0; mt < 4; ++mt)
                #pragma unroll
                for (int nt = 0; nt < 4; ++nt)
                    acc[mt][nt] = __builtin_amdgcn_mfma_f32_16x16x32_f16(
                        a[mt], b[nt], acc[mt][nt], 0, 0, 0);
        }
        __syncthreads();
    }

    #pragma unroll
    for (int nt = 0; nt < 4; ++nt) {
        const int n     = n0 + wn * 64 + nt * 16 + l16;
        const int which = n >> 10;                 // block-uniform (1024 % 128 == 0)
        const int rem   = n & 1023;
        const int head  = rem >> 6;
        const int d     = rem & 63;
        if (which == 2) {
            // V^T: r-run is contiguous in li -> packed 8 B stores
            #pragma unroll
            for (int mt = 0; mt < 4; ++mt) {
                const int m  = m0 + wm * 64 + mt * 16 + g * 4;
                const int bb = m >> 11;
                const int li = m & 2047;
                const int bh_i = bb * HEADS + head;
                uint2 pk;
                pk.x = (unsigned)f2h(acc[mt][nt][0]) | ((unsigned)f2h(acc[mt][nt][1]) << 16);
                pk.y = (unsigned)f2h(acc[mt][nt][2]) | ((unsigned)f2h(acc[mt][nt][3]) << 16);
                *reinterpret_cast<uint2*>(vtb + ((long)bh_i * DH + d) * SEQ + li) = pk;
            }
        } else {
            #pragma unroll
            for (int mt = 0; mt < 4; ++mt) {
                #pragma unroll
                for (int r = 0; r < 4; ++r) {
                    const int m  = m0 + wm * 64 + mt * 16 + g * 4 + r;
                    const int bb = m >> 11;
                    const int li = m & 2047;
                    const int bh_i = bb * HEADS + head;
                    const float val = acc[mt][nt][r];
                    if (which == 0)
                        qb[((long)bh_i * SEQ + li) * DH + d] = f2h(val * (SCALE * LOG2E));
                    else
                        kb[((long)bh_i * SEQ + li) * DH + d] = f2h(val);
                }
            }
        }
    }
}

// ---------------------------------------------------------------------------
// GEMM 2 (round-0 verified): glds16 + __syncthreads, 64x64 tiles, 4/CU.
// ---------------------------------------------------------------------------
__global__ __launch_bounds__(256, 4) void gemm_out_f16(
    const unsigned short* __restrict__ Ahg, const unsigned short* __restrict__ Bhg,
    const float* __restrict__ bias, float* __restrict__ out) {
    __shared__ __align__(16) unsigned short As[64 * 64];
    __shared__ __align__(16) unsigned short Bs[64 * 64];

    const int n0   = blockIdx.x * 64;
    const int m0   = blockIdx.y * 64;
    const int wave = threadIdx.x >> 6;
    const int lane = threadIdx.x & 63;
    const int l16  = lane & 15;
    const int g    = lane >> 4;
    const int wm   = wave & 1;
    const int wn   = wave >> 1;
    const int sw   = l16 & 7;

    const int sr8 = lane >> 3;
    const int scg = (lane & 7) ^ sr8;

    f32x4 acc[2][2] = {};

    for (int k0 = 0; k0 < DIM; k0 += 64) {
        #pragma unroll
        for (int i = 0; i < 2; ++i) {
            const int row = wave * 16 + i * 8;
            glds16(Ahg + (long)(m0 + row + sr8) * DIM + k0 + scg * 8, &As[row * 64]);
            glds16(Bhg + (long)(n0 + row + sr8) * DIM + k0 + scg * 8, &Bs[row * 64]);
        }
        __syncthreads();

        half8 a[2][2];
        #pragma unroll
        for (int mt = 0; mt < 2; ++mt) {
            const int rbase = (wm * 32 + mt * 16 + l16) * 64;
            #pragma unroll
            for (int kc = 0; kc < 2; ++kc)
                a[mt][kc] = *reinterpret_cast<const half8*>(
                    &As[rbase + (((kc * 4 + g) ^ sw) * 8)]);
        }
        #pragma unroll
        for (int nt = 0; nt < 2; ++nt) {
            const int rbase = (wn * 32 + nt * 16 + l16) * 64;
            const half8 b0 = *reinterpret_cast<const half8*>(&Bs[rbase + (((0 + g) ^ sw) * 8)]);
            const half8 b1 = *reinterpret_cast<const half8*>(&Bs[rbase + (((4 + g) ^ sw) * 8)]);
            #pragma unroll
            for (int mt = 0; mt < 2; ++mt) {
                acc[mt][nt] = __builtin_amdgcn_mfma_f32_16x16x32_f16(a[mt][0], b0, acc[mt][nt], 0, 0, 0);
                acc[mt][nt] = __builtin_amdgcn_mfma_f32_16x16x32_f16(a[mt][1], b1, acc[mt][nt], 0, 0, 0);
            }
        }
        __syncthreads();
    }

    #pragma unroll
    for (int nt = 0; nt < 2; ++nt) {
        const int n  = n0 + wn * 32 + nt * 16 + l16;
        const float bv = bias[n];
        #pragma unroll
        for (int mt = 0; mt < 2; ++mt) {
            #pragma unroll
            for (int r = 0; r < 4; ++r) {
                const int m = m0 + wm * 32 + mt * 16 + g * 4 + r;
                out[(long)m * DIM + n] = acc[mt][nt][r] + bv;
            }
        }
    }
}

// ---------------------------------------------------------------------------
// MFMA flash attention v13.1 (round-9 verified, 61.6 us, no spill) — reverted
// exactly; round-10's V-hoist (+32 regs) overflowed the 128-reg VGPR+AGPR
// budget at 2 blocks/CU and spilled (WRITE 22.5 MB). Register headroom at
// this occupancy is ~24 regs — noted for future edits.
// ---------------------------------------------------------------------------
__global__ __launch_bounds__(512, 4) void attn_mfma(const unsigned short* __restrict__ qb,
                                                    const unsigned short* __restrict__ kb,
                                                    const unsigned short* __restrict__ vtb,
                                                    const unsigned short* __restrict__ mbits,
                                                    unsigned short* __restrict__ zh) {
    // XCD-clustered decode: flat%8 = XCD; 16 qt-blocks of (bb,h) share an XCD.
    const int flat = blockIdx.x;            // 0..511
    const int xcd  = flat & 7;
    const int rr   = flat >> 3;             // 0..63
    const int hh   = xcd + 8 * (rr >> 4);   // 0..31 packed (bb*16+h)
    const int qt   = rr & 15;               // 128 q-rows each
    const int h    = hh & 15;
    const int bb   = hh >> 4;
    const int bh   = bb * HEADS + h;
    const int wave = threadIdx.x >> 6;      // 0..7
    const int lane = threadIdx.x & 63;
    const int l16  = lane & 15;
    const int g    = lane >> 4;
    const int wm   = wave >> 1;             // row group 0..3 (32 rows each)
    const int wj   = wave & 1;              // j half

    const int myrow0 = qt * 128 + wm * 32;

    // 48 KB: [0,16384) KV shorts (wj*8192 + {K:0,V:4096} + off)
    //        [16384,24576) per-wave P (wave*1024 + off)
    // epilogue reuses [0, 8832 floats) = 35 KB as cmb.
    __shared__ __align__(16) unsigned short shm[24576];
    unsigned short* Ks = &shm[wj * 8192];
    unsigned short* Vs = &shm[wj * 8192 + 4096];
    unsigned short* Pw = &shm[16384 + wave * 1024];

    const int sr8 = lane >> 3;
    const int scg = (lane & 7) ^ sr8;
    const int sw  = l16 & 7;

    const unsigned short* qptr = qb + ((long)bh * SEQ + myrow0 + l16) * DH + g * 8;
    const half8 q0 = *reinterpret_cast<const half8*>(qptr);
    const half8 q1 = *reinterpret_cast<const half8*>(qptr + 32);
    const half8 q2 = *reinterpret_cast<const half8*>(qptr + 16 * DH);
    const half8 q3 = *reinterpret_cast<const half8*>(qptr + 16 * DH + 32);

    half8 ones;
    #pragma unroll
    for (int j = 0; j < 8; ++j) ones[j] = (_Float16)1.0f;

    f32x4 o0[4] = {}, o1[4] = {};
    f32x4 oz0 = {0.f, 0.f, 0.f, 0.f};
    f32x4 oz1 = {0.f, 0.f, 0.f, 0.f};

    const unsigned short* mb =
        mbits + (((long)bb * 128 + qt * 8 + wm * 2) * 32 + wj * 16) * 64 + lane;
    const long kbase = (long)bh * SEQ * DH;
    const long vbase = (long)bh * DH * SEQ;
    const int  jb    = wj * 1024;

    for (int it = 0; it < 16; ++it) {
        const int j0 = jb + it * 64;
        const unsigned int bits0 = mb[(long)it * 64];
        const unsigned int bits1 = mb[(long)it * 64 + 2048];

        // ---- stage K/V tile (per wj half): 4 waves cover rows 0..63 ----
        #pragma unroll
        for (int i = 0; i < 2; ++i) {
            const int row = wm * 16 + i * 8;           // wave-uniform
            glds16(kb  + kbase + (long)(j0 + row + sr8) * DH + scg * 8, Ks + row * 64);
            glds16(vtb + vbase + (long)(row + sr8) * SEQ + j0 + scg * 8, Vs + row * 64);
        }
        __syncthreads();

        // ---- S^T = K Q^T both q-tiles; softmax fused; tile0 P -> LDS,
        //      tile1 P packed in regs ----
        uint2 p1s[4];
        #pragma unroll
        for (int nt = 0; nt < 4; ++nt) {
            const int rbase = (nt * 16 + l16) * 64;
            const half8 k0 = *reinterpret_cast<const half8*>(&Ks[rbase + ((0 + g) ^ sw) * 8]);
            const half8 k1 = *reinterpret_cast<const half8*>(&Ks[rbase + (((4 + g) ^ sw) * 8)]);
            f32x4 s0 = {0.f, 0.f, 0.f, 0.f};
            f32x4 s1 = {0.f, 0.f, 0.f, 0.f};
            s0 = __builtin_amdgcn_mfma_f32_16x16x32_f16(k0, q0, s0, 0, 0, 0);
            s0 = __builtin_amdgcn_mfma_f32_16x16x32_f16(k1, q1, s0, 0, 0, 0);
            s1 = __builtin_amdgcn_mfma_f32_16x16x32_f16(k0, q2, s1, 0, 0, 0);
            s1 = __builtin_amdgcn_mfma_f32_16x16x32_f16(k1, q3, s1, 0, 0, 0);

            float pa[4], pb[4];
            #pragma unroll
            for (int r = 0; r < 4; ++r) {
                const float e0 = __builtin_amdgcn_exp2f(s0[r]);
                const float e1 = __builtin_amdgcn_exp2f(s1[r]);
                pa[r] = ((bits0 >> (nt * 4 + r)) & 1u) ? e0 : 0.f;
                pb[r] = ((bits1 >> (nt * 4 + r)) & 1u) ? e1 : 0.f;
            }
            const int poff = l16 * 64 + (((2 * nt + (g >> 1)) ^ sw) * 8) + (g & 1) * 4;
            uint2 pk0;
            pk0.x = pkrtz(pa[0], pa[1]);
            pk0.y = pkrtz(pa[2], pa[3]);
            *reinterpret_cast<uint2*>(&Pw[poff]) = pk0;
            p1s[nt].x = pkrtz(pb[0], pb[1]);
            p1s[nt].y = pkrtz(pb[2], pb[3]);
        }

        // ---- tile0 P fragments, then overwrite Pw with tile1 (wave-private,
        //      lgkm-ordered: reads complete before aliasing writes) ----
        const half8 pb00 = *reinterpret_cast<const half8*>(&Pw[l16 * 64 + ((0 + g) ^ sw) * 8]);
        const half8 pb01 = *reinterpret_cast<const half8*>(&Pw[l16 * 64 + (((4 + g) ^ sw) * 8)]);
        #pragma unroll
        for (int nt = 0; nt < 4; ++nt) {
            const int poff = l16 * 64 + (((2 * nt + (g >> 1)) ^ sw) * 8) + (g & 1) * 4;
            *reinterpret_cast<uint2*>(&Pw[poff]) = p1s[nt];
        }
        const half8 pb10 = *reinterpret_cast<const half8*>(&Pw[l16 * 64 + ((0 + g) ^ sw) * 8]);
        const half8 pb11 = *reinterpret_cast<const half8*>(&Pw[l16 * 64 + (((4 + g) ^ sw) * 8)]);

        // ---- V fragments once; each feeds both q-tiles' PV ----
        #pragma unroll
        for (int dt = 0; dt < 4; ++dt) {
            const int vb = (dt * 16 + l16) * 64;
            const half8 v0 = *reinterpret_cast<const half8*>(&Vs[vb + ((0 + g) ^ sw) * 8]);
            const half8 v1 = *reinterpret_cast<const half8*>(&Vs[vb + (((4 + g) ^ sw) * 8)]);
            o0[dt] = __builtin_amdgcn_mfma_f32_16x16x32_f16(v0, pb00, o0[dt], 0, 0, 0);
            o0[dt] = __builtin_amdgcn_mfma_f32_16x16x32_f16(v1, pb01, o0[dt], 0, 0, 0);
            o1[dt] = __builtin_amdgcn_mfma_f32_16x16x32_f16(v0, pb10, o1[dt], 0, 0, 0);
            o1[dt] = __builtin_amdgcn_mfma_f32_16x16x32_f16(v1, pb11, o1[dt], 0, 0, 0);
        }
        oz0 = __builtin_amdgcn_mfma_f32_16x16x32_f16(ones, pb00, oz0, 0, 0, 0);
        oz0 = __builtin_amdgcn_mfma_f32_16x16x32_f16(ones, pb01, oz0, 0, 0, 0);
        oz1 = __builtin_amdgcn_mfma_f32_16x16x32_f16(ones, pb10, oz1, 0, 0, 0);
        oz1 = __builtin_amdgcn_mfma_f32_16x16x32_f16(ones, pb11, oz1, 0, 0, 0);
        __syncthreads();    // release KV tile for next staging round
    }

    // ---- combine the two j-halves (linear partials) ----
    float* cmb = (float*)shm;               // 128*68 + 128 floats = 35 KB <= 48 KB
    const int ZOFF = 128 * 68;
    const int ci0  = wm * 32 + l16;
    const int ci1  = ci0 + 16;
    if (wj == 1) {
        #pragma unroll
        for (int dt = 0; dt < 4; ++dt) {
            *reinterpret_cast<f32x4*>(&cmb[ci0 * 68 + dt * 16 + g * 4]) = o0[dt];
            *reinterpret_cast<f32x4*>(&cmb[ci1 * 68 + dt * 16 + g * 4]) = o1[dt];
        }
        if (g == 0) {
            cmb[ZOFF + ci0] = oz0[0];
            cmb[ZOFF + ci1] = oz1[0];
        }
    }
    __syncthreads();
    if (wj == 0) {
        const float Z0   = oz0[0] + cmb[ZOFF + ci0];
        const float Z1   = oz1[0] + cmb[ZOFF + ci1];
        const float inv0 = 1.f / (Z0 + 1e-30f);
        const float inv1 = 1.f / (Z1 + 1e-30f);
        const long obase0 = ((long)bb * SEQ + myrow0 + l16) * DIM + h * DH;
        const long obase1 = obase0 + (long)16 * DIM;
        #pragma unroll
        for (int dt = 0; dt < 4; ++dt) {
            const f32x4 oc0 = *reinterpret_cast<const f32x4*>(&cmb[ci0 * 68 + dt * 16 + g * 4]);
            const f32x4 oc1 = *reinterpret_cast<const f32x4*>(&cmb[ci1 * 68 + dt * 16 + g * 4]);
            uint2 pk;
            pk.x = pkrtz((o0[dt][0] + oc0[0]) * inv0, (o0[dt][1] + oc0[1]) * inv0);
            pk.y = pkrtz((o0[dt][2] + oc0[2]) * inv0, (o0[dt][3] + oc0[3]) * inv0);
            *reinterpret_cast<uint2*>(zh + obase0 + dt * 16 + g * 4) = pk;
            pk.x = pkrtz((o1[dt][0] + oc1[0]) * inv1, (o1[dt][1] + oc1[1]) * inv1);
            pk.y = pkrtz((o1[dt][2] + oc1[2]) * inv1, (o1[dt][3] + oc1[3]) * inv1);
            *reinterpret_cast<uint2*>(zh + obase1 + dt * 16 + g * 4) = pk;
        }
    }
}

// ---------------------------------------------------------------------------
extern "C" void kernel_launch(void* const* d_in, const int* in_sizes, int n_in,
                              void* d_out, int out_size, void* d_ws, size_t ws_size,
                              hipStream_t stream) {
    const float* x     = (const float*)d_in[0];
    const float* mask  = (const float*)d_in[1];
    const float* W_qkv = (const float*)d_in[2];
    const float* W_out = (const float*)d_in[3];
    const float* b_out = (const float*)d_in[4];
    float* out = (float*)d_out;

    unsigned short* ws = (unsigned short*)d_ws;
    unsigned short* xh    = ws;                  // 4M fp16 (reused as z after gemm1)
    unsigned short* WqT   = xh    + 4194304;     // 3M fp16
    unsigned short* WoT   = WqT   + 3145728;     // 1M fp16
    unsigned short* qbu   = WoT   + 1048576;     // 4M fp16
    unsigned short* kbu   = qbu   + 4194304;     // 4M fp16
    unsigned short* vtb   = kbu   + 4194304;     // 4M fp16
    unsigned short* mbits = vtb   + 4194304;     // 0.5M -> 41 MB total
    unsigned short* zz    = xh;

    prepass<<<8448, 256, 0, stream>>>(x, xh, W_qkv, WqT, W_out, WoT, mask, mbits);

    gemm_qkv_f16<<<768, 256, 0, stream>>>(xh, WqT, qbu, kbu, vtb);

    attn_mfma<<<512, 512, 0, stream>>>(qbu, kbu, vtb, mbits, zz);

    gemm_out_f16<<<dim3(16, 64), 256, 0, stream>>>(zz, WoT, b_out, out);
}

// Round 12
// 217.885 us; speedup vs baseline: 1.4508x; 1.0182x over previous
//
#include <hip/hip_runtime.h>
#include <hip/hip_bf16.h>

// x: [2, 2048, 1024] f32; mask: [2, 2048, 2048] f32; W_qkv: [1024, 3072] f32
// W_out: [1024, 1024] f32; b_out: [1024] f32; out: [2, 2048, 1024] f32
#define BATCH 2
#define SEQ   2048
#define DIM   1024
#define HEADS 16
#define DH    64
#define N_QKV 3072
#define M_TOT 4096
#define SCALE 0.125f
#define EPS   1e-10f
#define LOG2E 1.442695041f

typedef __attribute__((ext_vector_type(8))) _Float16 half8;
typedef __attribute__((ext_vector_type(4))) float f32x4;

static __device__ __forceinline__ unsigned short f2h(float f) {
    _Float16 h = (_Float16)f;
    return __builtin_bit_cast(unsigned short, h);
}
static __device__ __forceinline__ unsigned int pkrtz(float a, float b) {
#if defined(__has_builtin) && __has_builtin(__builtin_amdgcn_cvt_pkrtz)
    return __builtin_bit_cast(unsigned int, __builtin_amdgcn_cvt_pkrtz(a, b));
#else
    return (unsigned int)f2h(a) | ((unsigned int)f2h(b) << 16);
#endif
}
static __device__ __forceinline__ void glds16(const void* g, void* l) {
    __builtin_amdgcn_global_load_lds((const __attribute__((address_space(1))) void*)g,
                                     (__attribute__((address_space(3))) void*)l,
                                     16, 0, 0);
}

// ---------------------------------------------------------------------------
// Merged pre-pass v2 (this round): mask job vectorized — float4 loads
// (128 scalar -> 32 vec4 loads/thread) and barriers 16 -> 4 (2 c0-passes of
// 1024 cols instead of 8 of 256). Bit-pack layout unchanged:
// jt = (c0>>6)+tl+4s; bit(nt*4+r) <- flags[ln&15][cb+nt*16+(ln>>4)*4+r].
// x-convert and W-transpose jobs unchanged (round-0 verified).
// ---------------------------------------------------------------------------
__global__ __launch_bounds__(256) void prepass(const float* __restrict__ x,
                                               unsigned short* __restrict__ xh,
                                               const float* __restrict__ Wq,
                                               unsigned short* __restrict__ WqT,
                                               const float* __restrict__ Wo,
                                               unsigned short* __restrict__ WoT,
                                               const float* __restrict__ mask,
                                               unsigned short* __restrict__ mbits) {
    const int bid = blockIdx.x;
    const int t   = threadIdx.x;
    __shared__ float tile[32][33];
    __shared__ unsigned char flags[16][1024];

    if (bid < 4096) {
        const int i = bid * 256 + t;
        float4 v = reinterpret_cast<const float4*>(x)[i];
        uint2 o;
        o.x = pkrtz(v.x, v.y);
        o.y = pkrtz(v.z, v.w);
        reinterpret_cast<uint2*>(xh)[i] = o;
    } else if (bid < 8192) {
        const float* src; unsigned short* th; int rows, cols, bx;
        if (bid < 7168) { src = Wq; th = WqT; rows = 1024; cols = 3072; bx = bid - 4096;
        } else          { src = Wo; th = WoT; rows = 1024; cols = 1024; bx = bid - 7168; }
        const int nbx = cols / 32;
        const int c0 = (bx % nbx) * 32, r0 = (bx / nbx) * 32;
        const int tx = t & 31, ty = t >> 5;
        #pragma unroll
        for (int i = ty; i < 32; i += 8)
            tile[i][tx] = src[(long)(r0 + i) * cols + c0 + tx];
        __syncthreads();
        #pragma unroll
        for (int i = ty; i < 32; i += 8)
            th[(long)(c0 + i) * rows + r0 + tx] = f2h(tile[tx][i]);
    } else {
        const int bx = bid - 8192;
        const int it = bx & 127;
        const int bb = bx >> 7;
        const int R0 = it * 16;
        const int tl = t >> 6, ln = t & 63;
        const int lr = ln & 15;              // q-row within tile
        const int lg = (ln >> 4) << 2;       // col sub-group base
        for (int c0 = 0; c0 < SEQ; c0 += 1024) {
            #pragma unroll
            for (int rr = 0; rr < 16; ++rr) {
                const float4 v = *reinterpret_cast<const float4*>(
                    mask + ((long)bb * SEQ + R0 + rr) * SEQ + c0 + t * 4);
                flags[rr][t * 4 + 0] = v.x != 0.f;
                flags[rr][t * 4 + 1] = v.y != 0.f;
                flags[rr][t * 4 + 2] = v.z != 0.f;
                flags[rr][t * 4 + 3] = v.w != 0.f;
            }
            __syncthreads();
            #pragma unroll
            for (int s = 0; s < 4; ++s) {
                const int jt = tl + 4 * s;           // j-tile within this pass
                const int cb = jt * 64;
                unsigned int bits = 0;
                #pragma unroll
                for (int nt = 0; nt < 4; ++nt)
                    #pragma unroll
                    for (int r = 0; r < 4; ++r)
                        bits |= (unsigned int)flags[lr][cb + nt * 16 + lg + r]
                                << (nt * 4 + r);
                mbits[(((long)bb * 128 + it) * 32 + (c0 >> 6) + jt) * 64 + ln] =
                    (unsigned short)bits;
            }
            __syncthreads();
        }
    }
}

// ---------------------------------------------------------------------------
// GEMM 1 v6 (round-11 verified): 128x128/BK=64/glds16 + XCD-rect dispatch
// (8 rects of 8m x 12n) + packed vtb stores.
// ---------------------------------------------------------------------------
__global__ __launch_bounds__(256, 3) void gemm_qkv_f16(
    const unsigned short* __restrict__ Ahg, const unsigned short* __restrict__ Bhg,
    unsigned short* __restrict__ qb, unsigned short* __restrict__ kb,
    unsigned short* __restrict__ vtb) {
    __shared__ __align__(16) unsigned short As[128 * 64];   // 16 KB
    __shared__ __align__(16) unsigned short Bs[128 * 64];   // 16 KB

    // XCD-tile decode: f%8 = XCD (round-robin dispatch); each XCD owns an
    // 8m x 12n rectangle of the 32x24 block grid. Bijective: 8*96 = 768.
    const int f   = blockIdx.x;
    const int xcd = f & 7;
    const int c   = f >> 3;              // 0..95 within-XCD
    const int rm  = xcd & 3;             // 4 rect-rows
    const int rn  = xcd >> 2;            // 2 rect-cols
    const int by  = rm * 8 + c / 12;     // 0..31
    const int bx  = rn * 12 + c % 12;    // 0..23
    const int n0  = bx * 128;
    const int m0  = by * 128;

    const int wave = threadIdx.x >> 6;
    const int lane = threadIdx.x & 63;
    const int l16  = lane & 15;
    const int g    = lane >> 4;
    const int wm   = wave & 1;
    const int wn   = wave >> 1;
    const int sw   = l16 & 7;

    const int sr8 = lane >> 3;
    const int scg = (lane & 7) ^ sr8;

    f32x4 acc[4][4] = {};

    for (int k0 = 0; k0 < DIM; k0 += 64) {
        #pragma unroll
        for (int i = 0; i < 4; ++i) {
            const int row = wave * 32 + i * 8;     // wave-uniform; covers 0..127
            glds16(Ahg + (long)(m0 + row + sr8) * DIM + k0 + scg * 8, &As[row * 64]);
            glds16(Bhg + (long)(n0 + row + sr8) * DIM + k0 + scg * 8, &Bs[row * 64]);
        }
        __syncthreads();

        #pragma unroll
        for (int kc = 0; kc < 2; ++kc) {
            half8 a[4], b[4];
            #pragma unroll
            for (int mt = 0; mt < 4; ++mt)
                a[mt] = *reinterpret_cast<const half8*>(
                    &As[(wm * 64 + mt * 16 + l16) * 64 + (((kc * 4 + g) ^ sw) * 8)]);
            #pragma unroll
            for (int nt = 0; nt < 4; ++nt)
                b[nt] = *reinterpret_cast<const half8*>(
                    &Bs[(wn * 64 + nt * 16 + l16) * 64 + (((kc * 4 + g) ^ sw) * 8)]);
            #pragma unroll
            for (int mt = 0; mt < 4; ++mt)
                #pragma unroll
                for (int nt = 0; nt < 4; ++nt)
                    acc[mt][nt] = __builtin_amdgcn_mfma_f32_16x16x32_f16(
                        a[mt], b[nt], acc[mt][nt], 0, 0, 0);
        }
        __syncthreads();
    }

    #pragma unroll
    for (int nt = 0; nt < 4; ++nt) {
        const int n     = n0 + wn * 64 + nt * 16 + l16;
        const int which = n >> 10;                 // block-uniform (1024 % 128 == 0)
        const int rem   = n & 1023;
        const int head  = rem >> 6;
        const int d     = rem & 63;
        if (which == 2) {
            // V^T: r-run is contiguous in li -> packed 8 B stores
            #pragma unroll
            for (int mt = 0; mt < 4; ++mt) {
                const int m  = m0 + wm * 64 + mt * 16 + g * 4;
                const int bb = m >> 11;
                const int li = m & 2047;
                const int bh_i = bb * HEADS + head;
                uint2 pk;
                pk.x = (unsigned)f2h(acc[mt][nt][0]) | ((unsigned)f2h(acc[mt][nt][1]) << 16);
                pk.y = (unsigned)f2h(acc[mt][nt][2]) | ((unsigned)f2h(acc[mt][nt][3]) << 16);
                *reinterpret_cast<uint2*>(vtb + ((long)bh_i * DH + d) * SEQ + li) = pk;
            }
        } else {
            #pragma unroll
            for (int mt = 0; mt < 4; ++mt) {
                #pragma unroll
                for (int r = 0; r < 4; ++r) {
                    const int m  = m0 + wm * 64 + mt * 16 + g * 4 + r;
                    const int bb = m >> 11;
                    const int li = m & 2047;
                    const int bh_i = bb * HEADS + head;
                    const float val = acc[mt][nt][r];
                    if (which == 0)
                        qb[((long)bh_i * SEQ + li) * DH + d] = f2h(val * (SCALE * LOG2E));
                    else
                        kb[((long)bh_i * SEQ + li) * DH + d] = f2h(val);
                }
            }
        }
    }
}

// ---------------------------------------------------------------------------
// GEMM 2 v3 (this round): round-0 verified 64x64 compute with XCD-rect
// dispatch (T1, verified on qkv r11 / attn r5-r11): flat 1024 grid, each
// XCD owns an 8by x 16bx rectangle -> its 1 MB A-slab + full 2 MB WoT are
// L2-resident. Bijective: 8 * 128 = 1024.
// ---------------------------------------------------------------------------
__global__ __launch_bounds__(256, 4) void gemm_out_f16(
    const unsigned short* __restrict__ Ahg, const unsigned short* __restrict__ Bhg,
    const float* __restrict__ bias, float* __restrict__ out) {
    __shared__ __align__(16) unsigned short As[64 * 64];
    __shared__ __align__(16) unsigned short Bs[64 * 64];

    const int f   = blockIdx.x;
    const int xcd = f & 7;
    const int c   = f >> 3;              // 0..127 within-XCD
    const int by  = xcd * 8 + (c >> 4);  // 0..63
    const int bx  = c & 15;              // 0..15
    const int n0  = bx * 64;
    const int m0  = by * 64;

    const int wave = threadIdx.x >> 6;
    const int lane = threadIdx.x & 63;
    const int l16  = lane & 15;
    const int g    = lane >> 4;
    const int wm   = wave & 1;
    const int wn   = wave >> 1;
    const int sw   = l16 & 7;

    const int sr8 = lane >> 3;
    const int scg = (lane & 7) ^ sr8;

    f32x4 acc[2][2] = {};

    for (int k0 = 0; k0 < DIM; k0 += 64) {
        #pragma unroll
        for (int i = 0; i < 2; ++i) {
            const int row = wave * 16 + i * 8;
            glds16(Ahg + (long)(m0 + row + sr8) * DIM + k0 + scg * 8, &As[row * 64]);
            glds16(Bhg + (long)(n0 + row + sr8) * DIM + k0 + scg * 8, &Bs[row * 64]);
        }
        __syncthreads();

        half8 a[2][2];
        #pragma unroll
        for (int mt = 0; mt < 2; ++mt) {
            const int rbase = (wm * 32 + mt * 16 + l16) * 64;
            #pragma unroll
            for (int kc = 0; kc < 2; ++kc)
                a[mt][kc] = *reinterpret_cast<const half8*>(
                    &As[rbase + (((kc * 4 + g) ^ sw) * 8)]);
        }
        #pragma unroll
        for (int nt = 0; nt < 2; ++nt) {
            const int rbase = (wn * 32 + nt * 16 + l16) * 64;
            const half8 b0 = *reinterpret_cast<const half8*>(&Bs[rbase + (((0 + g) ^ sw) * 8)]);
            const half8 b1 = *reinterpret_cast<const half8*>(&Bs[rbase + (((4 + g) ^ sw) * 8)]);
            #pragma unroll
            for (int mt = 0; mt < 2; ++mt) {
                acc[mt][nt] = __builtin_amdgcn_mfma_f32_16x16x32_f16(a[mt][0], b0, acc[mt][nt], 0, 0, 0);
                acc[mt][nt] = __builtin_amdgcn_mfma_f32_16x16x32_f16(a[mt][1], b1, acc[mt][nt], 0, 0, 0);
            }
        }
        __syncthreads();
    }

    #pragma unroll
    for (int nt = 0; nt < 2; ++nt) {
        const int n  = n0 + wn * 32 + nt * 16 + l16;
        const float bv = bias[n];
        #pragma unroll
        for (int mt = 0; mt < 2; ++mt) {
            #pragma unroll
            for (int r = 0; r < 4; ++r) {
                const int m = m0 + wm * 32 + mt * 16 + g * 4 + r;
                out[(long)m * DIM + n] = acc[mt][nt][r] + bv;
            }
        }
    }
}

// ---------------------------------------------------------------------------
// MFMA flash attention v13.1 (round-9/11 verified, 61.2 us, no spill).
// Register headroom at 2 blocks/CU is ~24 regs (r10 lesson) — do not add
// register state here.
// ---------------------------------------------------------------------------
__global__ __launch_bounds__(512, 4) void attn_mfma(const unsigned short* __restrict__ qb,
                                                    const unsigned short* __restrict__ kb,
                                                    const unsigned short* __restrict__ vtb,
                                                    const unsigned short* __restrict__ mbits,
                                                    unsigned short* __restrict__ zh) {
    // XCD-clustered decode: flat%8 = XCD; 16 qt-blocks of (bb,h) share an XCD.
    const int flat = blockIdx.x;            // 0..511
    const int xcd  = flat & 7;
    const int rr   = flat >> 3;             // 0..63
    const int hh   = xcd + 8 * (rr >> 4);   // 0..31 packed (bb*16+h)
    const int qt   = rr & 15;               // 128 q-rows each
    const int h    = hh & 15;
    const int bb   = hh >> 4;
    const int bh   = bb * HEADS + h;
    const int wave = threadIdx.x >> 6;      // 0..7
    const int lane = threadIdx.x & 63;
    const int l16  = lane & 15;
    const int g    = lane >> 4;
    const int wm   = wave >> 1;             // row group 0..3 (32 rows each)
    const int wj   = wave & 1;              // j half

    const int myrow0 = qt * 128 + wm * 32;

    // 48 KB: [0,16384) KV shorts (wj*8192 + {K:0,V:4096} + off)
    //        [16384,24576) per-wave P (wave*1024 + off)
    // epilogue reuses [0, 8832 floats) = 35 KB as cmb.
    __shared__ __align__(16) unsigned short shm[24576];
    unsigned short* Ks = &shm[wj * 8192];
    unsigned short* Vs = &shm[wj * 8192 + 4096];
    unsigned short* Pw = &shm[16384 + wave * 1024];

    const int sr8 = lane >> 3;
    const int scg = (lane & 7) ^ sr8;
    const int sw  = l16 & 7;

    const unsigned short* qptr = qb + ((long)bh * SEQ + myrow0 + l16) * DH + g * 8;
    const half8 q0 = *reinterpret_cast<const half8*>(qptr);
    const half8 q1 = *reinterpret_cast<const half8*>(qptr + 32);
    const half8 q2 = *reinterpret_cast<const half8*>(qptr + 16 * DH);
    const half8 q3 = *reinterpret_cast<const half8*>(qptr + 16 * DH + 32);

    half8 ones;
    #pragma unroll
    for (int j = 0; j < 8; ++j) ones[j] = (_Float16)1.0f;

    f32x4 o0[4] = {}, o1[4] = {};
    f32x4 oz0 = {0.f, 0.f, 0.f, 0.f};
    f32x4 oz1 = {0.f, 0.f, 0.f, 0.f};

    const unsigned short* mb =
        mbits + (((long)bb * 128 + qt * 8 + wm * 2) * 32 + wj * 16) * 64 + lane;
    const long kbase = (long)bh * SEQ * DH;
    const long vbase = (long)bh * DH * SEQ;
    const int  jb    = wj * 1024;

    for (int it = 0; it < 16; ++it) {
        const int j0 = jb + it * 64;
        const unsigned int bits0 = mb[(long)it * 64];
        const unsigned int bits1 = mb[(long)it * 64 + 2048];

        // ---- stage K/V tile (per wj half): 4 waves cover rows 0..63 ----
        #pragma unroll
        for (int i = 0; i < 2; ++i) {
            const int row = wm * 16 + i * 8;           // wave-uniform
            glds16(kb  + kbase + (long)(j0 + row + sr8) * DH + scg * 8, Ks + row * 64);
            glds16(vtb + vbase + (long)(row + sr8) * SEQ + j0 + scg * 8, Vs + row * 64);
        }
        __syncthreads();

        // ---- S^T = K Q^T both q-tiles; softmax fused; tile0 P -> LDS,
        //      tile1 P packed in regs ----
        uint2 p1s[4];
        #pragma unroll
        for (int nt = 0; nt < 4; ++nt) {
            const int rbase = (nt * 16 + l16) * 64;
            const half8 k0 = *reinterpret_cast<const half8*>(&Ks[rbase + ((0 + g) ^ sw) * 8]);
            const half8 k1 = *reinterpret_cast<const half8*>(&Ks[rbase + (((4 + g) ^ sw) * 8)]);
            f32x4 s0 = {0.f, 0.f, 0.f, 0.f};
            f32x4 s1 = {0.f, 0.f, 0.f, 0.f};
            s0 = __builtin_amdgcn_mfma_f32_16x16x32_f16(k0, q0, s0, 0, 0, 0);
            s0 = __builtin_amdgcn_mfma_f32_16x16x32_f16(k1, q1, s0, 0, 0, 0);
            s1 = __builtin_amdgcn_mfma_f32_16x16x32_f16(k0, q2, s1, 0, 0, 0);
            s1 = __builtin_amdgcn_mfma_f32_16x16x32_f16(k1, q3, s1, 0, 0, 0);

            float pa[4], pb[4];
            #pragma unroll
            for (int r = 0; r < 4; ++r) {
                const float e0 = __builtin_amdgcn_exp2f(s0[r]);
                const float e1 = __builtin_amdgcn_exp2f(s1[r]);
                pa[r] = ((bits0 >> (nt * 4 + r)) & 1u) ? e0 : 0.f;
                pb[r] = ((bits1 >> (nt * 4 + r)) & 1u) ? e1 : 0.f;
            }
            const int poff = l16 * 64 + (((2 * nt + (g >> 1)) ^ sw) * 8) + (g & 1) * 4;
            uint2 pk0;
            pk0.x = pkrtz(pa[0], pa[1]);
            pk0.y = pkrtz(pa[2], pa[3]);
            *reinterpret_cast<uint2*>(&Pw[poff]) = pk0;
            p1s[nt].x = pkrtz(pb[0], pb[1]);
            p1s[nt].y = pkrtz(pb[2], pb[3]);
        }

        // ---- tile0 P fragments, then overwrite Pw with tile1 (wave-private,
        //      lgkm-ordered: reads complete before aliasing writes) ----
        const half8 pb00 = *reinterpret_cast<const half8*>(&Pw[l16 * 64 + ((0 + g) ^ sw) * 8]);
        const half8 pb01 = *reinterpret_cast<const half8*>(&Pw[l16 * 64 + (((4 + g) ^ sw) * 8)]);
        #pragma unroll
        for (int nt = 0; nt < 4; ++nt) {
            const int poff = l16 * 64 + (((2 * nt + (g >> 1)) ^ sw) * 8) + (g & 1) * 4;
            *reinterpret_cast<uint2*>(&Pw[poff]) = p1s[nt];
        }
        const half8 pb10 = *reinterpret_cast<const half8*>(&Pw[l16 * 64 + ((0 + g) ^ sw) * 8]);
        const half8 pb11 = *reinterpret_cast<const half8*>(&Pw[l16 * 64 + (((4 + g) ^ sw) * 8)]);

        // ---- V fragments once; each feeds both q-tiles' PV ----
        #pragma unroll
        for (int dt = 0; dt < 4; ++dt) {
            const int vb = (dt * 16 + l16) * 64;
            const half8 v0 = *reinterpret_cast<const half8*>(&Vs[vb + ((0 + g) ^ sw) * 8]);
            const half8 v1 = *reinterpret_cast<const half8*>(&Vs[vb + (((4 + g) ^ sw) * 8)]);
            o0[dt] = __builtin_amdgcn_mfma_f32_16x16x32_f16(v0, pb00, o0[dt], 0, 0, 0);
            o0[dt] = __builtin_amdgcn_mfma_f32_16x16x32_f16(v1, pb01, o0[dt], 0, 0, 0);
            o1[dt] = __builtin_amdgcn_mfma_f32_16x16x32_f16(v0, pb10, o1[dt], 0, 0, 0);
            o1[dt] = __builtin_amdgcn_mfma_f32_16x16x32_f16(v1, pb11, o1[dt], 0, 0, 0);
        }
        oz0 = __builtin_amdgcn_mfma_f32_16x16x32_f16(ones, pb00, oz0, 0, 0, 0);
        oz0 = __builtin_amdgcn_mfma_f32_16x16x32_f16(ones, pb01, oz0, 0, 0, 0);
        oz1 = __builtin_amdgcn_mfma_f32_16x16x32_f16(ones, pb10, oz1, 0, 0, 0);
        oz1 = __builtin_amdgcn_mfma_f32_16x16x32_f16(ones, pb11, oz1, 0, 0, 0);
        __syncthreads();    // release KV tile for next staging round
    }

    // ---- combine the two j-halves (linear partials) ----
    float* cmb = (float*)shm;               // 128*68 + 128 floats = 35 KB <= 48 KB
    const int ZOFF = 128 * 68;
    const int ci0  = wm * 32 + l16;
    const int ci1  = ci0 + 16;
    if (wj == 1) {
        #pragma unroll
        for (int dt = 0; dt < 4; ++dt) {
            *reinterpret_cast<f32x4*>(&cmb[ci0 * 68 + dt * 16 + g * 4]) = o0[dt];
            *reinterpret_cast<f32x4*>(&cmb[ci1 * 68 + dt * 16 + g * 4]) = o1[dt];
        }
        if (g == 0) {
            cmb[ZOFF + ci0] = oz0[0];
            cmb[ZOFF + ci1] = oz1[0];
        }
    }
    __syncthreads();
    if (wj == 0) {
        const float Z0   = oz0[0] + cmb[ZOFF + ci0];
        const float Z1   = oz1[0] + cmb[ZOFF + ci1];
        const float inv0 = 1.f / (Z0 + 1e-30f);
        const float inv1 = 1.f / (Z1 + 1e-30f);
        const long obase0 = ((long)bb * SEQ + myrow0 + l16) * DIM + h * DH;
        const long obase1 = obase0 + (long)16 * DIM;
        #pragma unroll
        for (int dt = 0; dt < 4; ++dt) {
            const f32x4 oc0 = *reinterpret_cast<const f32x4*>(&cmb[ci0 * 68 + dt * 16 + g * 4]);
            const f32x4 oc1 = *reinterpret_cast<const f32x4*>(&cmb[ci1 * 68 + dt * 16 + g * 4]);
            uint2 pk;
            pk.x = pkrtz((o0[dt][0] + oc0[0]) * inv0, (o0[dt][1] + oc0[1]) * inv0);
            pk.y = pkrtz((o0[dt][2] + oc0[2]) * inv0, (o0[dt][3] + oc0[3]) * inv0);
            *reinterpret_cast<uint2*>(zh + obase0 + dt * 16 + g * 4) = pk;
            pk.x = pkrtz((o1[dt][0] + oc1[0]) * inv1, (o1[dt][1] + oc1[1]) * inv1);
            pk.y = pkrtz((o1[dt][2] + oc1[2]) * inv1, (o1[dt][3] + oc1[3]) * inv1);
            *reinterpret_cast<uint2*>(zh + obase1 + dt * 16 + g * 4) = pk;
        }
    }
}

// ---------------------------------------------------------------------------
extern "C" void kernel_launch(void* const* d_in, const int* in_sizes, int n_in,
                              void* d_out, int out_size, void* d_ws, size_t ws_size,
                              hipStream_t stream) {
    const float* x     = (const float*)d_in[0];
    const float* mask  = (const float*)d_in[1];
    const float* W_qkv = (const float*)d_in[2];
    const float* W_out = (const float*)d_in[3];
    const float* b_out = (const float*)d_in[4];
    float* out = (float*)d_out;

    unsigned short* ws = (unsigned short*)d_ws;
    unsigned short* xh    = ws;                  // 4M fp16 (reused as z after gemm1)
    unsigned short* WqT   = xh    + 4194304;     // 3M fp16
    unsigned short* WoT   = WqT   + 3145728;     // 1M fp16
    unsigned short* qbu   = WoT   + 1048576;     // 4M fp16
    unsigned short* kbu   = qbu   + 4194304;     // 4M fp16
    unsigned short* vtb   = kbu   + 4194304;     // 4M fp16
    unsigned short* mbits = vtb   + 4194304;     // 0.5M -> 41 MB total
    unsigned short* zz    = xh;

    prepass<<<8448, 256, 0, stream>>>(x, xh, W_qkv, WqT, W_out, WoT, mask, mbits);

    gemm_qkv_f16<<<768, 256, 0, stream>>>(xh, WqT, qbu, kbu, vtb);

    attn_mfma<<<512, 512, 0, stream>>>(qbu, kbu, vtb, mbits, zz);

    gemm_out_f16<<<1024, 256, 0, stream>>>(zz, WoT, b_out, out);
}

// Round 13
// 215.935 us; speedup vs baseline: 1.4639x; 1.0090x over previous
//
#include <hip/hip_runtime.h>
#include <hip/hip_bf16.h>

// x: [2, 2048, 1024] f32; mask: [2, 2048, 2048] f32; W_qkv: [1024, 3072] f32
// W_out: [1024, 1024] f32; b_out: [1024] f32; out: [2, 2048, 1024] f32
#define BATCH 2
#define SEQ   2048
#define DIM   1024
#define HEADS 16
#define DH    64
#define N_QKV 3072
#define M_TOT 4096
#define SCALE 0.125f
#define EPS   1e-10f
#define LOG2E 1.442695041f

typedef __attribute__((ext_vector_type(8))) _Float16 half8;
typedef __attribute__((ext_vector_type(4))) float f32x4;

static __device__ __forceinline__ unsigned short f2h(float f) {
    _Float16 h = (_Float16)f;
    return __builtin_bit_cast(unsigned short, h);
}
static __device__ __forceinline__ unsigned int pkrtz(float a, float b) {
#if defined(__has_builtin) && __has_builtin(__builtin_amdgcn_cvt_pkrtz)
    return __builtin_bit_cast(unsigned int, __builtin_amdgcn_cvt_pkrtz(a, b));
#else
    return (unsigned int)f2h(a) | ((unsigned int)f2h(b) << 16);
#endif
}
static __device__ __forceinline__ void glds16(const void* g, void* l) {
    __builtin_amdgcn_global_load_lds((const __attribute__((address_space(1))) void*)g,
                                     (__attribute__((address_space(3))) void*)l,
                                     16, 0, 0);
}

// ---------------------------------------------------------------------------
// Merged pre-pass v3 (this round): mask job split 4x along columns
// (256 -> 1024 blocks) — it ran as a 1-block/CU serial tail. Each block now
// handles one 512-col chunk (float2 loads, 2 barriers). Bit-pack layout
// unchanged: jt_global = cq*8 + tl + 4s; bit(nt*4+r) <-
// flags[ln&15][jt_local*64 + nt*16 + (ln>>4)*4 + r].
// x-convert and W-transpose jobs unchanged (round-0 verified).
// ---------------------------------------------------------------------------
__global__ __launch_bounds__(256) void prepass(const float* __restrict__ x,
                                               unsigned short* __restrict__ xh,
                                               const float* __restrict__ Wq,
                                               unsigned short* __restrict__ WqT,
                                               const float* __restrict__ Wo,
                                               unsigned short* __restrict__ WoT,
                                               const float* __restrict__ mask,
                                               unsigned short* __restrict__ mbits) {
    const int bid = blockIdx.x;
    const int t   = threadIdx.x;
    __shared__ float tile[32][33];
    __shared__ unsigned char flags[16][512];

    if (bid < 4096) {
        const int i = bid * 256 + t;
        float4 v = reinterpret_cast<const float4*>(x)[i];
        uint2 o;
        o.x = pkrtz(v.x, v.y);
        o.y = pkrtz(v.z, v.w);
        reinterpret_cast<uint2*>(xh)[i] = o;
    } else if (bid < 8192) {
        const float* src; unsigned short* th; int rows, cols, bx;
        if (bid < 7168) { src = Wq; th = WqT; rows = 1024; cols = 3072; bx = bid - 4096;
        } else          { src = Wo; th = WoT; rows = 1024; cols = 1024; bx = bid - 7168; }
        const int nbx = cols / 32;
        const int c0 = (bx % nbx) * 32, r0 = (bx / nbx) * 32;
        const int tx = t & 31, ty = t >> 5;
        #pragma unroll
        for (int i = ty; i < 32; i += 8)
            tile[i][tx] = src[(long)(r0 + i) * cols + c0 + tx];
        __syncthreads();
        #pragma unroll
        for (int i = ty; i < 32; i += 8)
            th[(long)(c0 + i) * rows + r0 + tx] = f2h(tile[tx][i]);
    } else {
        const int bx2 = bid - 8192;             // 0..1023
        const int cq  = bx2 & 3;                // column chunk: c0 = cq*512
        const int it  = (bx2 >> 2) & 127;       // 16-row tile
        const int bb  = bx2 >> 9;               // batch
        const int R0  = it * 16;
        const int c0  = cq * 512;
        const int tl = t >> 6, ln = t & 63;
        const int lr = ln & 15;                 // q-row within tile
        const int lg = (ln >> 4) << 2;          // col sub-group base

        #pragma unroll
        for (int rr = 0; rr < 16; ++rr) {
            const float2 v = *reinterpret_cast<const float2*>(
                mask + ((long)bb * SEQ + R0 + rr) * SEQ + c0 + t * 2);
            flags[rr][t * 2 + 0] = v.x != 0.f;
            flags[rr][t * 2 + 1] = v.y != 0.f;
        }
        __syncthreads();
        #pragma unroll
        for (int s = 0; s < 2; ++s) {
            const int jt_local = tl + 4 * s;    // 0..7 within chunk
            const int cb = jt_local * 64;
            unsigned int bits = 0;
            #pragma unroll
            for (int nt = 0; nt < 4; ++nt)
                #pragma unroll
                for (int r = 0; r < 4; ++r)
                    bits |= (unsigned int)flags[lr][cb + nt * 16 + lg + r]
                            << (nt * 4 + r);
            mbits[(((long)bb * 128 + it) * 32 + cq * 8 + jt_local) * 64 + ln] =
                (unsigned short)bits;
        }
    }
}

// ---------------------------------------------------------------------------
// GEMM 1 v6 (round-11 verified): 128x128/BK=64/glds16 + XCD-rect dispatch
// (8 rects of 8m x 12n) + packed vtb stores.
// ---------------------------------------------------------------------------
__global__ __launch_bounds__(256, 3) void gemm_qkv_f16(
    const unsigned short* __restrict__ Ahg, const unsigned short* __restrict__ Bhg,
    unsigned short* __restrict__ qb, unsigned short* __restrict__ kb,
    unsigned short* __restrict__ vtb) {
    __shared__ __align__(16) unsigned short As[128 * 64];   // 16 KB
    __shared__ __align__(16) unsigned short Bs[128 * 64];   // 16 KB

    // XCD-tile decode: f%8 = XCD (round-robin dispatch); each XCD owns an
    // 8m x 12n rectangle of the 32x24 block grid. Bijective: 8*96 = 768.
    const int f   = blockIdx.x;
    const int xcd = f & 7;
    const int c   = f >> 3;              // 0..95 within-XCD
    const int rm  = xcd & 3;             // 4 rect-rows
    const int rn  = xcd >> 2;            // 2 rect-cols
    const int by  = rm * 8 + c / 12;     // 0..31
    const int bx  = rn * 12 + c % 12;    // 0..23
    const int n0  = bx * 128;
    const int m0  = by * 128;

    const int wave = threadIdx.x >> 6;
    const int lane = threadIdx.x & 63;
    const int l16  = lane & 15;
    const int g    = lane >> 4;
    const int wm   = wave & 1;
    const int wn   = wave >> 1;
    const int sw   = l16 & 7;

    const int sr8 = lane >> 3;
    const int scg = (lane & 7) ^ sr8;

    f32x4 acc[4][4] = {};

    for (int k0 = 0; k0 < DIM; k0 += 64) {
        #pragma unroll
        for (int i = 0; i < 4; ++i) {
            const int row = wave * 32 + i * 8;     // wave-uniform; covers 0..127
            glds16(Ahg + (long)(m0 + row + sr8) * DIM + k0 + scg * 8, &As[row * 64]);
            glds16(Bhg + (long)(n0 + row + sr8) * DIM + k0 + scg * 8, &Bs[row * 64]);
        }
        __syncthreads();

        #pragma unroll
        for (int kc = 0; kc < 2; ++kc) {
            half8 a[4], b[4];
            #pragma unroll
            for (int mt = 0; mt < 4; ++mt)
                a[mt] = *reinterpret_cast<const half8*>(
                    &As[(wm * 64 + mt * 16 + l16) * 64 + (((kc * 4 + g) ^ sw) * 8)]);
            #pragma unroll
            for (int nt = 0; nt < 4; ++nt)
                b[nt] = *reinterpret_cast<const half8*>(
                    &Bs[(wn * 64 + nt * 16 + l16) * 64 + (((kc * 4 + g) ^ sw) * 8)]);
            #pragma unroll
            for (int mt = 0; mt < 4; ++mt)
                #pragma unroll
                for (int nt = 0; nt < 4; ++nt)
                    acc[mt][nt] = __builtin_amdgcn_mfma_f32_16x16x32_f16(
                        a[mt], b[nt], acc[mt][nt], 0, 0, 0);
        }
        __syncthreads();
    }

    #pragma unroll
    for (int nt = 0; nt < 4; ++nt) {
        const int n     = n0 + wn * 64 + nt * 16 + l16;
        const int which = n >> 10;                 // block-uniform (1024 % 128 == 0)
        const int rem   = n & 1023;
        const int head  = rem >> 6;
        const int d     = rem & 63;
        if (which == 2) {
            // V^T: r-run is contiguous in li -> packed 8 B stores
            #pragma unroll
            for (int mt = 0; mt < 4; ++mt) {
                const int m  = m0 + wm * 64 + mt * 16 + g * 4;
                const int bb = m >> 11;
                const int li = m & 2047;
                const int bh_i = bb * HEADS + head;
                uint2 pk;
                pk.x = (unsigned)f2h(acc[mt][nt][0]) | ((unsigned)f2h(acc[mt][nt][1]) << 16);
                pk.y = (unsigned)f2h(acc[mt][nt][2]) | ((unsigned)f2h(acc[mt][nt][3]) << 16);
                *reinterpret_cast<uint2*>(vtb + ((long)bh_i * DH + d) * SEQ + li) = pk;
            }
        } else {
            #pragma unroll
            for (int mt = 0; mt < 4; ++mt) {
                #pragma unroll
                for (int r = 0; r < 4; ++r) {
                    const int m  = m0 + wm * 64 + mt * 16 + g * 4 + r;
                    const int bb = m >> 11;
                    const int li = m & 2047;
                    const int bh_i = bb * HEADS + head;
                    const float val = acc[mt][nt][r];
                    if (which == 0)
                        qb[((long)bh_i * SEQ + li) * DH + d] = f2h(val * (SCALE * LOG2E));
                    else
                        kb[((long)bh_i * SEQ + li) * DH + d] = f2h(val);
                }
            }
        }
    }
}

// ---------------------------------------------------------------------------
// GEMM 2 v3 (round-12 verified): 64x64 + XCD-rect dispatch (8 rects of
// 8by x 16bx, bijective 8*128 = 1024).
// ---------------------------------------------------------------------------
__global__ __launch_bounds__(256, 4) void gemm_out_f16(
    const unsigned short* __restrict__ Ahg, const unsigned short* __restrict__ Bhg,
    const float* __restrict__ bias, float* __restrict__ out) {
    __shared__ __align__(16) unsigned short As[64 * 64];
    __shared__ __align__(16) unsigned short Bs[64 * 64];

    const int f   = blockIdx.x;
    const int xcd = f & 7;
    const int c   = f >> 3;              // 0..127 within-XCD
    const int by  = xcd * 8 + (c >> 4);  // 0..63
    const int bx  = c & 15;              // 0..15
    const int n0  = bx * 64;
    const int m0  = by * 64;

    const int wave = threadIdx.x >> 6;
    const int lane = threadIdx.x & 63;
    const int l16  = lane & 15;
    const int g    = lane >> 4;
    const int wm   = wave & 1;
    const int wn   = wave >> 1;
    const int sw   = l16 & 7;

    const int sr8 = lane >> 3;
    const int scg = (lane & 7) ^ sr8;

    f32x4 acc[2][2] = {};

    for (int k0 = 0; k0 < DIM; k0 += 64) {
        #pragma unroll
        for (int i = 0; i < 2; ++i) {
            const int row = wave * 16 + i * 8;
            glds16(Ahg + (long)(m0 + row + sr8) * DIM + k0 + scg * 8, &As[row * 64]);
            glds16(Bhg + (long)(n0 + row + sr8) * DIM + k0 + scg * 8, &Bs[row * 64]);
        }
        __syncthreads();

        half8 a[2][2];
        #pragma unroll
        for (int mt = 0; mt < 2; ++mt) {
            const int rbase = (wm * 32 + mt * 16 + l16) * 64;
            #pragma unroll
            for (int kc = 0; kc < 2; ++kc)
                a[mt][kc] = *reinterpret_cast<const half8*>(
                    &As[rbase + (((kc * 4 + g) ^ sw) * 8)]);
        }
        #pragma unroll
        for (int nt = 0; nt < 2; ++nt) {
            const int rbase = (wn * 32 + nt * 16 + l16) * 64;
            const half8 b0 = *reinterpret_cast<const half8*>(&Bs[rbase + (((0 + g) ^ sw) * 8)]);
            const half8 b1 = *reinterpret_cast<const half8*>(&Bs[rbase + (((4 + g) ^ sw) * 8)]);
            #pragma unroll
            for (int mt = 0; mt < 2; ++mt) {
                acc[mt][nt] = __builtin_amdgcn_mfma_f32_16x16x32_f16(a[mt][0], b0, acc[mt][nt], 0, 0, 0);
                acc[mt][nt] = __builtin_amdgcn_mfma_f32_16x16x32_f16(a[mt][1], b1, acc[mt][nt], 0, 0, 0);
            }
        }
        __syncthreads();
    }

    #pragma unroll
    for (int nt = 0; nt < 2; ++nt) {
        const int n  = n0 + wn * 32 + nt * 16 + l16;
        const float bv = bias[n];
        #pragma unroll
        for (int mt = 0; mt < 2; ++mt) {
            #pragma unroll
            for (int r = 0; r < 4; ++r) {
                const int m = m0 + wm * 32 + mt * 16 + g * 4 + r;
                out[(long)m * DIM + n] = acc[mt][nt][r] + bv;
            }
        }
    }
}

// ---------------------------------------------------------------------------
// MFMA flash attention v13.1 (round-9/11/12 verified, 61.3 us, no spill).
// Register headroom at 2 blocks/CU is ~24 regs (r10 lesson) — do not add
// register state here.
// ---------------------------------------------------------------------------
__global__ __launch_bounds__(512, 4) void attn_mfma(const unsigned short* __restrict__ qb,
                                                    const unsigned short* __restrict__ kb,
                                                    const unsigned short* __restrict__ vtb,
                                                    const unsigned short* __restrict__ mbits,
                                                    unsigned short* __restrict__ zh) {
    // XCD-clustered decode: flat%8 = XCD; 16 qt-blocks of (bb,h) share an XCD.
    const int flat = blockIdx.x;            // 0..511
    const int xcd  = flat & 7;
    const int rr   = flat >> 3;             // 0..63
    const int hh   = xcd + 8 * (rr >> 4);   // 0..31 packed (bb*16+h)
    const int qt   = rr & 15;               // 128 q-rows each
    const int h    = hh & 15;
    const int bb   = hh >> 4;
    const int bh   = bb * HEADS + h;
    const int wave = threadIdx.x >> 6;      // 0..7
    const int lane = threadIdx.x & 63;
    const int l16  = lane & 15;
    const int g    = lane >> 4;
    const int wm   = wave >> 1;             // row group 0..3 (32 rows each)
    const int wj   = wave & 1;              // j half

    const int myrow0 = qt * 128 + wm * 32;

    // 48 KB: [0,16384) KV shorts (wj*8192 + {K:0,V:4096} + off)
    //        [16384,24576) per-wave P (wave*1024 + off)
    // epilogue reuses [0, 8832 floats) = 35 KB as cmb.
    __shared__ __align__(16) unsigned short shm[24576];
    unsigned short* Ks = &shm[wj * 8192];
    unsigned short* Vs = &shm[wj * 8192 + 4096];
    unsigned short* Pw = &shm[16384 + wave * 1024];

    const int sr8 = lane >> 3;
    const int scg = (lane & 7) ^ sr8;
    const int sw  = l16 & 7;

    const unsigned short* qptr = qb + ((long)bh * SEQ + myrow0 + l16) * DH + g * 8;
    const half8 q0 = *reinterpret_cast<const half8*>(qptr);
    const half8 q1 = *reinterpret_cast<const half8*>(qptr + 32);
    const half8 q2 = *reinterpret_cast<const half8*>(qptr + 16 * DH);
    const half8 q3 = *reinterpret_cast<const half8*>(qptr + 16 * DH + 32);

    half8 ones;
    #pragma unroll
    for (int j = 0; j < 8; ++j) ones[j] = (_Float16)1.0f;

    f32x4 o0[4] = {}, o1[4] = {};
    f32x4 oz0 = {0.f, 0.f, 0.f, 0.f};
    f32x4 oz1 = {0.f, 0.f, 0.f, 0.f};

    const unsigned short* mb =
        mbits + (((long)bb * 128 + qt * 8 + wm * 2) * 32 + wj * 16) * 64 + lane;
    const long kbase = (long)bh * SEQ * DH;
    const long vbase = (long)bh * DH * SEQ;
    const int  jb    = wj * 1024;

    for (int it = 0; it < 16; ++it) {
        const int j0 = jb + it * 64;
        const unsigned int bits0 = mb[(long)it * 64];
        const unsigned int bits1 = mb[(long)it * 64 + 2048];

        // ---- stage K/V tile (per wj half): 4 waves cover rows 0..63 ----
        #pragma unroll
        for (int i = 0; i < 2; ++i) {
            const int row = wm * 16 + i * 8;           // wave-uniform
            glds16(kb  + kbase + (long)(j0 + row + sr8) * DH + scg * 8, Ks + row * 64);
            glds16(vtb + vbase + (long)(row + sr8) * SEQ + j0 + scg * 8, Vs + row * 64);
        }
        __syncthreads();

        // ---- S^T = K Q^T both q-tiles; softmax fused; tile0 P -> LDS,
        //      tile1 P packed in regs ----
        uint2 p1s[4];
        #pragma unroll
        for (int nt = 0; nt < 4; ++nt) {
            const int rbase = (nt * 16 + l16) * 64;
            const half8 k0 = *reinterpret_cast<const half8*>(&Ks[rbase + ((0 + g) ^ sw) * 8]);
            const half8 k1 = *reinterpret_cast<const half8*>(&Ks[rbase + (((4 + g) ^ sw) * 8)]);
            f32x4 s0 = {0.f, 0.f, 0.f, 0.f};
            f32x4 s1 = {0.f, 0.f, 0.f, 0.f};
            s0 = __builtin_amdgcn_mfma_f32_16x16x32_f16(k0, q0, s0, 0, 0, 0);
            s0 = __builtin_amdgcn_mfma_f32_16x16x32_f16(k1, q1, s0, 0, 0, 0);
            s1 = __builtin_amdgcn_mfma_f32_16x16x32_f16(k0, q2, s1, 0, 0, 0);
            s1 = __builtin_amdgcn_mfma_f32_16x16x32_f16(k1, q3, s1, 0, 0, 0);

            float pa[4], pb[4];
            #pragma unroll
            for (int r = 0; r < 4; ++r) {
                const float e0 = __builtin_amdgcn_exp2f(s0[r]);
                const float e1 = __builtin_amdgcn_exp2f(s1[r]);
                pa[r] = ((bits0 >> (nt * 4 + r)) & 1u) ? e0 : 0.f;
                pb[r] = ((bits1 >> (nt * 4 + r)) & 1u) ? e1 : 0.f;
            }
            const int poff = l16 * 64 + (((2 * nt + (g >> 1)) ^ sw) * 8) + (g & 1) * 4;
            uint2 pk0;
            pk0.x = pkrtz(pa[0], pa[1]);
            pk0.y = pkrtz(pa[2], pa[3]);
            *reinterpret_cast<uint2*>(&Pw[poff]) = pk0;
            p1s[nt].x = pkrtz(pb[0], pb[1]);
            p1s[nt].y = pkrtz(pb[2], pb[3]);
        }

        // ---- tile0 P fragments, then overwrite Pw with tile1 (wave-private,
        //      lgkm-ordered: reads complete before aliasing writes) ----
        const half8 pb00 = *reinterpret_cast<const half8*>(&Pw[l16 * 64 + ((0 + g) ^ sw) * 8]);
        const half8 pb01 = *reinterpret_cast<const half8*>(&Pw[l16 * 64 + (((4 + g) ^ sw) * 8)]);
        #pragma unroll
        for (int nt = 0; nt < 4; ++nt) {
            const int poff = l16 * 64 + (((2 * nt + (g >> 1)) ^ sw) * 8) + (g & 1) * 4;
            *reinterpret_cast<uint2*>(&Pw[poff]) = p1s[nt];
        }
        const half8 pb10 = *reinterpret_cast<const half8*>(&Pw[l16 * 64 + ((0 + g) ^ sw) * 8]);
        const half8 pb11 = *reinterpret_cast<const half8*>(&Pw[l16 * 64 + (((4 + g) ^ sw) * 8)]);

        // ---- V fragments once; each feeds both q-tiles' PV ----
        #pragma unroll
        for (int dt = 0; dt < 4; ++dt) {
            const int vb = (dt * 16 + l16) * 64;
            const half8 v0 = *reinterpret_cast<const half8*>(&Vs[vb + ((0 + g) ^ sw) * 8]);
            const half8 v1 = *reinterpret_cast<const half8*>(&Vs[vb + (((4 + g) ^ sw) * 8)]);
            o0[dt] = __builtin_amdgcn_mfma_f32_16x16x32_f16(v0, pb00, o0[dt], 0, 0, 0);
            o0[dt] = __builtin_amdgcn_mfma_f32_16x16x32_f16(v1, pb01, o0[dt], 0, 0, 0);
            o1[dt] = __builtin_amdgcn_mfma_f32_16x16x32_f16(v0, pb10, o1[dt], 0, 0, 0);
            o1[dt] = __builtin_amdgcn_mfma_f32_16x16x32_f16(v1, pb11, o1[dt], 0, 0, 0);
        }
        oz0 = __builtin_amdgcn_mfma_f32_16x16x32_f16(ones, pb00, oz0, 0, 0, 0);
        oz0 = __builtin_amdgcn_mfma_f32_16x16x32_f16(ones, pb01, oz0, 0, 0, 0);
        oz1 = __builtin_amdgcn_mfma_f32_16x16x32_f16(ones, pb10, oz1, 0, 0, 0);
        oz1 = __builtin_amdgcn_mfma_f32_16x16x32_f16(ones, pb11, oz1, 0, 0, 0);
        __syncthreads();    // release KV tile for next staging round
    }

    // ---- combine the two j-halves (linear partials) ----
    float* cmb = (float*)shm;               // 128*68 + 128 floats = 35 KB <= 48 KB
    const int ZOFF = 128 * 68;
    const int ci0  = wm * 32 + l16;
    const int ci1  = ci0 + 16;
    if (wj == 1) {
        #pragma unroll
        for (int dt = 0; dt < 4; ++dt) {
            *reinterpret_cast<f32x4*>(&cmb[ci0 * 68 + dt * 16 + g * 4]) = o0[dt];
            *reinterpret_cast<f32x4*>(&cmb[ci1 * 68 + dt * 16 + g * 4]) = o1[dt];
        }
        if (g == 0) {
            cmb[ZOFF + ci0] = oz0[0];
            cmb[ZOFF + ci1] = oz1[0];
        }
    }
    __syncthreads();
    if (wj == 0) {
        const float Z0   = oz0[0] + cmb[ZOFF + ci0];
        const float Z1   = oz1[0] + cmb[ZOFF + ci1];
        const float inv0 = 1.f / (Z0 + 1e-30f);
        const float inv1 = 1.f / (Z1 + 1e-30f);
        const long obase0 = ((long)bb * SEQ + myrow0 + l16) * DIM + h * DH;
        const long obase1 = obase0 + (long)16 * DIM;
        #pragma unroll
        for (int dt = 0; dt < 4; ++dt) {
            const f32x4 oc0 = *reinterpret_cast<const f32x4*>(&cmb[ci0 * 68 + dt * 16 + g * 4]);
            const f32x4 oc1 = *reinterpret_cast<const f32x4*>(&cmb[ci1 * 68 + dt * 16 + g * 4]);
            uint2 pk;
            pk.x = pkrtz((o0[dt][0] + oc0[0]) * inv0, (o0[dt][1] + oc0[1]) * inv0);
            pk.y = pkrtz((o0[dt][2] + oc0[2]) * inv0, (o0[dt][3] + oc0[3]) * inv0);
            *reinterpret_cast<uint2*>(zh + obase0 + dt * 16 + g * 4) = pk;
            pk.x = pkrtz((o1[dt][0] + oc1[0]) * inv1, (o1[dt][1] + oc1[1]) * inv1);
            pk.y = pkrtz((o1[dt][2] + oc1[2]) * inv1, (o1[dt][3] + oc1[3]) * inv1);
            *reinterpret_cast<uint2*>(zh + obase1 + dt * 16 + g * 4) = pk;
        }
    }
}

// ---------------------------------------------------------------------------
extern "C" void kernel_launch(void* const* d_in, const int* in_sizes, int n_in,
                              void* d_out, int out_size, void* d_ws, size_t ws_size,
                              hipStream_t stream) {
    const float* x     = (const float*)d_in[0];
    const float* mask  = (const float*)d_in[1];
    const float* W_qkv = (const float*)d_in[2];
    const float* W_out = (const float*)d_in[3];
    const float* b_out = (const float*)d_in[4];
    float* out = (float*)d_out;

    unsigned short* ws = (unsigned short*)d_ws;
    unsigned short* xh    = ws;                  // 4M fp16 (reused as z after gemm1)
    unsigned short* WqT   = xh    + 4194304;     // 3M fp16
    unsigned short* WoT   = WqT   + 3145728;     // 1M fp16
    unsigned short* qbu   = WoT   + 1048576;     // 4M fp16
    unsigned short* kbu   = qbu   + 4194304;     // 4M fp16
    unsigned short* vtb   = kbu   + 4194304;     // 4M fp16
    unsigned short* mbits = vtb   + 4194304;     // 0.5M -> 41 MB total
    unsigned short* zz    = xh;

    prepass<<<9216, 256, 0, stream>>>(x, xh, W_qkv, WqT, W_out, WoT, mask, mbits);

    gemm_qkv_f16<<<768, 256, 0, stream>>>(xh, WqT, qbu, kbu, vtb);

    attn_mfma<<<512, 512, 0, stream>>>(qbu, kbu, vtb, mbits, zz);

    gemm_out_f16<<<1024, 256, 0, stream>>>(zz, WoT, b_out, out);
}

// Round 14
// 211.080 us; speedup vs baseline: 1.4975x; 1.0230x over previous
//
#include <hip/hip_runtime.h>
#include <hip/hip_bf16.h>

// x: [2, 2048, 1024] f32; mask: [2, 2048, 2048] f32; W_qkv: [1024, 3072] f32
// W_out: [1024, 1024] f32; b_out: [1024] f32; out: [2, 2048, 1024] f32
#define BATCH 2
#define SEQ   2048
#define DIM   1024
#define HEADS 16
#define DH    64
#define N_QKV 3072
#define M_TOT 4096
#define SCALE 0.125f
#define EPS   1e-10f
#define LOG2E 1.442695041f

typedef __attribute__((ext_vector_type(8))) _Float16 half8;
typedef __attribute__((ext_vector_type(4))) float f32x4;

static __device__ __forceinline__ unsigned short f2h(float f) {
    _Float16 h = (_Float16)f;
    return __builtin_bit_cast(unsigned short, h);
}
static __device__ __forceinline__ unsigned int pkrtz(float a, float b) {
#if defined(__has_builtin) && __has_builtin(__builtin_amdgcn_cvt_pkrtz)
    return __builtin_bit_cast(unsigned int, __builtin_amdgcn_cvt_pkrtz(a, b));
#else
    return (unsigned int)f2h(a) | ((unsigned int)f2h(b) << 16);
#endif
}
static __device__ __forceinline__ void glds16(const void* g, void* l) {
    __builtin_amdgcn_global_load_lds((const __attribute__((address_space(1))) void*)g,
                                     (__attribute__((address_space(3))) void*)l,
                                     16, 0, 0);
}

// ---------------------------------------------------------------------------
// Merged pre-pass v3 (round-13 verified): mask job split 4x along columns
// (1024 blocks, float2 loads); x-convert and W-transpose unchanged.
// ---------------------------------------------------------------------------
__global__ __launch_bounds__(256) void prepass(const float* __restrict__ x,
                                               unsigned short* __restrict__ xh,
                                               const float* __restrict__ Wq,
                                               unsigned short* __restrict__ WqT,
                                               const float* __restrict__ Wo,
                                               unsigned short* __restrict__ WoT,
                                               const float* __restrict__ mask,
                                               unsigned short* __restrict__ mbits) {
    const int bid = blockIdx.x;
    const int t   = threadIdx.x;
    __shared__ float tile[32][33];
    __shared__ unsigned char flags[16][512];

    if (bid < 4096) {
        const int i = bid * 256 + t;
        float4 v = reinterpret_cast<const float4*>(x)[i];
        uint2 o;
        o.x = pkrtz(v.x, v.y);
        o.y = pkrtz(v.z, v.w);
        reinterpret_cast<uint2*>(xh)[i] = o;
    } else if (bid < 8192) {
        const float* src; unsigned short* th; int rows, cols, bx;
        if (bid < 7168) { src = Wq; th = WqT; rows = 1024; cols = 3072; bx = bid - 4096;
        } else          { src = Wo; th = WoT; rows = 1024; cols = 1024; bx = bid - 7168; }
        const int nbx = cols / 32;
        const int c0 = (bx % nbx) * 32, r0 = (bx / nbx) * 32;
        const int tx = t & 31, ty = t >> 5;
        #pragma unroll
        for (int i = ty; i < 32; i += 8)
            tile[i][tx] = src[(long)(r0 + i) * cols + c0 + tx];
        __syncthreads();
        #pragma unroll
        for (int i = ty; i < 32; i += 8)
            th[(long)(c0 + i) * rows + r0 + tx] = f2h(tile[tx][i]);
    } else {
        const int bx2 = bid - 8192;             // 0..1023
        const int cq  = bx2 & 3;                // column chunk: c0 = cq*512
        const int it  = (bx2 >> 2) & 127;       // 16-row tile
        const int bb  = bx2 >> 9;               // batch
        const int R0  = it * 16;
        const int c0  = cq * 512;
        const int tl = t >> 6, ln = t & 63;
        const int lr = ln & 15;                 // q-row within tile
        const int lg = (ln >> 4) << 2;          // col sub-group base

        #pragma unroll
        for (int rr = 0; rr < 16; ++rr) {
            const float2 v = *reinterpret_cast<const float2*>(
                mask + ((long)bb * SEQ + R0 + rr) * SEQ + c0 + t * 2);
            flags[rr][t * 2 + 0] = v.x != 0.f;
            flags[rr][t * 2 + 1] = v.y != 0.f;
        }
        __syncthreads();
        #pragma unroll
        for (int s = 0; s < 2; ++s) {
            const int jt_local = tl + 4 * s;    // 0..7 within chunk
            const int cb = jt_local * 64;
            unsigned int bits = 0;
            #pragma unroll
            for (int nt = 0; nt < 4; ++nt)
                #pragma unroll
                for (int r = 0; r < 4; ++r)
                    bits |= (unsigned int)flags[lr][cb + nt * 16 + lg + r]
                            << (nt * 4 + r);
            mbits[(((long)bb * 128 + it) * 32 + cq * 8 + jt_local) * 64 + ln] =
                (unsigned short)bits;
        }
    }
}

// ---------------------------------------------------------------------------
// GEMM 1 v6 (round-11 verified): 128x128/BK=64/glds16 + XCD-rect dispatch
// (8 rects of 8m x 12n) + packed vtb stores.
// ---------------------------------------------------------------------------
__global__ __launch_bounds__(256, 3) void gemm_qkv_f16(
    const unsigned short* __restrict__ Ahg, const unsigned short* __restrict__ Bhg,
    unsigned short* __restrict__ qb, unsigned short* __restrict__ kb,
    unsigned short* __restrict__ vtb) {
    __shared__ __align__(16) unsigned short As[128 * 64];   // 16 KB
    __shared__ __align__(16) unsigned short Bs[128 * 64];   // 16 KB

    // XCD-tile decode: f%8 = XCD (round-robin dispatch); each XCD owns an
    // 8m x 12n rectangle of the 32x24 block grid. Bijective: 8*96 = 768.
    const int f   = blockIdx.x;
    const int xcd = f & 7;
    const int c   = f >> 3;              // 0..95 within-XCD
    const int rm  = xcd & 3;             // 4 rect-rows
    const int rn  = xcd >> 2;            // 2 rect-cols
    const int by  = rm * 8 + c / 12;     // 0..31
    const int bx  = rn * 12 + c % 12;    // 0..23
    const int n0  = bx * 128;
    const int m0  = by * 128;

    const int wave = threadIdx.x >> 6;
    const int lane = threadIdx.x & 63;
    const int l16  = lane & 15;
    const int g    = lane >> 4;
    const int wm   = wave & 1;
    const int wn   = wave >> 1;
    const int sw   = l16 & 7;

    const int sr8 = lane >> 3;
    const int scg = (lane & 7) ^ sr8;

    f32x4 acc[4][4] = {};

    for (int k0 = 0; k0 < DIM; k0 += 64) {
        #pragma unroll
        for (int i = 0; i < 4; ++i) {
            const int row = wave * 32 + i * 8;     // wave-uniform; covers 0..127
            glds16(Ahg + (long)(m0 + row + sr8) * DIM + k0 + scg * 8, &As[row * 64]);
            glds16(Bhg + (long)(n0 + row + sr8) * DIM + k0 + scg * 8, &Bs[row * 64]);
        }
        __syncthreads();

        #pragma unroll
        for (int kc = 0; kc < 2; ++kc) {
            half8 a[4], b[4];
            #pragma unroll
            for (int mt = 0; mt < 4; ++mt)
                a[mt] = *reinterpret_cast<const half8*>(
                    &As[(wm * 64 + mt * 16 + l16) * 64 + (((kc * 4 + g) ^ sw) * 8)]);
            #pragma unroll
            for (int nt = 0; nt < 4; ++nt)
                b[nt] = *reinterpret_cast<const half8*>(
                    &Bs[(wn * 64 + nt * 16 + l16) * 64 + (((kc * 4 + g) ^ sw) * 8)]);
            #pragma unroll
            for (int mt = 0; mt < 4; ++mt)
                #pragma unroll
                for (int nt = 0; nt < 4; ++nt)
                    acc[mt][nt] = __builtin_amdgcn_mfma_f32_16x16x32_f16(
                        a[mt], b[nt], acc[mt][nt], 0, 0, 0);
        }
        __syncthreads();
    }

    #pragma unroll
    for (int nt = 0; nt < 4; ++nt) {
        const int n     = n0 + wn * 64 + nt * 16 + l16;
        const int which = n >> 10;                 // block-uniform (1024 % 128 == 0)
        const int rem   = n & 1023;
        const int head  = rem >> 6;
        const int d     = rem & 63;
        if (which == 2) {
            // V^T: r-run is contiguous in li -> packed 8 B stores
            #pragma unroll
            for (int mt = 0; mt < 4; ++mt) {
                const int m  = m0 + wm * 64 + mt * 16 + g * 4;
                const int bb = m >> 11;
                const int li = m & 2047;
                const int bh_i = bb * HEADS + head;
                uint2 pk;
                pk.x = (unsigned)f2h(acc[mt][nt][0]) | ((unsigned)f2h(acc[mt][nt][1]) << 16);
                pk.y = (unsigned)f2h(acc[mt][nt][2]) | ((unsigned)f2h(acc[mt][nt][3]) << 16);
                *reinterpret_cast<uint2*>(vtb + ((long)bh_i * DH + d) * SEQ + li) = pk;
            }
        } else {
            #pragma unroll
            for (int mt = 0; mt < 4; ++mt) {
                #pragma unroll
                for (int r = 0; r < 4; ++r) {
                    const int m  = m0 + wm * 64 + mt * 16 + g * 4 + r;
                    const int bb = m >> 11;
                    const int li = m & 2047;
                    const int bh_i = bb * HEADS + head;
                    const float val = acc[mt][nt][r];
                    if (which == 0)
                        qb[((long)bh_i * SEQ + li) * DH + d] = f2h(val * (SCALE * LOG2E));
                    else
                        kb[((long)bh_i * SEQ + li) * DH + d] = f2h(val);
                }
            }
        }
    }
}

// ---------------------------------------------------------------------------
// GEMM 2 v3 (round-12 verified): 64x64 + XCD-rect dispatch (8 rects of
// 8by x 16bx, bijective 8*128 = 1024).
// ---------------------------------------------------------------------------
__global__ __launch_bounds__(256, 4) void gemm_out_f16(
    const unsigned short* __restrict__ Ahg, const unsigned short* __restrict__ Bhg,
    const float* __restrict__ bias, float* __restrict__ out) {
    __shared__ __align__(16) unsigned short As[64 * 64];
    __shared__ __align__(16) unsigned short Bs[64 * 64];

    const int f   = blockIdx.x;
    const int xcd = f & 7;
    const int c   = f >> 3;              // 0..127 within-XCD
    const int by  = xcd * 8 + (c >> 4);  // 0..63
    const int bx  = c & 15;              // 0..15
    const int n0  = bx * 64;
    const int m0  = by * 64;

    const int wave = threadIdx.x >> 6;
    const int lane = threadIdx.x & 63;
    const int l16  = lane & 15;
    const int g    = lane >> 4;
    const int wm   = wave & 1;
    const int wn   = wave >> 1;
    const int sw   = l16 & 7;

    const int sr8 = lane >> 3;
    const int scg = (lane & 7) ^ sr8;

    f32x4 acc[2][2] = {};

    for (int k0 = 0; k0 < DIM; k0 += 64) {
        #pragma unroll
        for (int i = 0; i < 2; ++i) {
            const int row = wave * 16 + i * 8;
            glds16(Ahg + (long)(m0 + row + sr8) * DIM + k0 + scg * 8, &As[row * 64]);
            glds16(Bhg + (long)(n0 + row + sr8) * DIM + k0 + scg * 8, &Bs[row * 64]);
        }
        __syncthreads();

        half8 a[2][2];
        #pragma unroll
        for (int mt = 0; mt < 2; ++mt) {
            const int rbase = (wm * 32 + mt * 16 + l16) * 64;
            #pragma unroll
            for (int kc = 0; kc < 2; ++kc)
                a[mt][kc] = *reinterpret_cast<const half8*>(
                    &As[rbase + (((kc * 4 + g) ^ sw) * 8)]);
        }
        #pragma unroll
        for (int nt = 0; nt < 2; ++nt) {
            const int rbase = (wn * 32 + nt * 16 + l16) * 64;
            const half8 b0 = *reinterpret_cast<const half8*>(&Bs[rbase + (((0 + g) ^ sw) * 8)]);
            const half8 b1 = *reinterpret_cast<const half8*>(&Bs[rbase + (((4 + g) ^ sw) * 8)]);
            #pragma unroll
            for (int mt = 0; mt < 2; ++mt) {
                acc[mt][nt] = __builtin_amdgcn_mfma_f32_16x16x32_f16(a[mt][0], b0, acc[mt][nt], 0, 0, 0);
                acc[mt][nt] = __builtin_amdgcn_mfma_f32_16x16x32_f16(a[mt][1], b1, acc[mt][nt], 0, 0, 0);
            }
        }
        __syncthreads();
    }

    #pragma unroll
    for (int nt = 0; nt < 2; ++nt) {
        const int n  = n0 + wn * 32 + nt * 16 + l16;
        const float bv = bias[n];
        #pragma unroll
        for (int mt = 0; mt < 2; ++mt) {
            #pragma unroll
            for (int r = 0; r < 4; ++r) {
                const int m = m0 + wm * 32 + mt * 16 + g * 4 + r;
                out[(long)m * DIM + n] = acc[mt][nt][r] + bv;
            }
        }
    }
}

// ---------------------------------------------------------------------------
// MFMA flash attention v15 (this round): v13.1 math with KVBLK 64 -> 128.
// Two j-subtiles staged per barrier interval; barrier/drain count 32 -> 16.
// r3's "1 barrier/iter neutral" null was measured on the LDS-pipe-bound
// v7.1 (rule 23: wrong regime); v13.1 has 0.55x the LDS reads and ~35% of
// cycles in neither pipe, so the drain fraction is now the candidate.
// LDS 80 KB (KV 64K = [2 sub][2 wj][K/V] + P 16K) -> 2 blocks/CU = 160 KB
// exact fit (verified on-device at r3: 81920 B => 2 blocks/CU).
// Registers unchanged (subtiles processed sequentially, p1s stays [4]).
// Spill sentinel: WRITE_SIZE must stay ~8 MB, VGPR ~64.
// ---------------------------------------------------------------------------
__global__ __launch_bounds__(512, 4) void attn_mfma(const unsigned short* __restrict__ qb,
                                                    const unsigned short* __restrict__ kb,
                                                    const unsigned short* __restrict__ vtb,
                                                    const unsigned short* __restrict__ mbits,
                                                    unsigned short* __restrict__ zh) {
    // XCD-clustered decode: flat%8 = XCD; 16 qt-blocks of (bb,h) share an XCD.
    const int flat = blockIdx.x;            // 0..511
    const int xcd  = flat & 7;
    const int rr   = flat >> 3;             // 0..63
    const int hh   = xcd + 8 * (rr >> 4);   // 0..31 packed (bb*16+h)
    const int qt   = rr & 15;               // 128 q-rows each
    const int h    = hh & 15;
    const int bb   = hh >> 4;
    const int bh   = bb * HEADS + h;
    const int wave = threadIdx.x >> 6;      // 0..7
    const int lane = threadIdx.x & 63;
    const int l16  = lane & 15;
    const int g    = lane >> 4;
    const int wm   = wave >> 1;             // row group 0..3 (32 rows each)
    const int wj   = wave & 1;              // j half

    const int myrow0 = qt * 128 + wm * 32;

    // 80 KB: [0,32768) KV shorts: sub*16384 + wj*8192 + {K:0,V:4096} + off
    //        [32768,40960) per-wave P (wave*1024 + off)
    // epilogue reuses [0, 8832 floats) = 35 KB as cmb.
    __shared__ __align__(16) unsigned short shm[40960];
    unsigned short* Pw = &shm[32768 + wave * 1024];

    const int sr8 = lane >> 3;
    const int scg = (lane & 7) ^ sr8;
    const int sw  = l16 & 7;

    const unsigned short* qptr = qb + ((long)bh * SEQ + myrow0 + l16) * DH + g * 8;
    const half8 q0 = *reinterpret_cast<const half8*>(qptr);
    const half8 q1 = *reinterpret_cast<const half8*>(qptr + 32);
    const half8 q2 = *reinterpret_cast<const half8*>(qptr + 16 * DH);
    const half8 q3 = *reinterpret_cast<const half8*>(qptr + 16 * DH + 32);

    half8 ones;
    #pragma unroll
    for (int j = 0; j < 8; ++j) ones[j] = (_Float16)1.0f;

    f32x4 o0[4] = {}, o1[4] = {};
    f32x4 oz0 = {0.f, 0.f, 0.f, 0.f};
    f32x4 oz1 = {0.f, 0.f, 0.f, 0.f};

    const unsigned short* mb =
        mbits + (((long)bb * 128 + qt * 8 + wm * 2) * 32 + wj * 16) * 64 + lane;
    const long kbase = (long)bh * SEQ * DH;
    const long vbase = (long)bh * DH * SEQ;
    const int  jb    = wj * 1024;

    for (int ith = 0; ith < 8; ++ith) {
        // ---- stage BOTH j-subtiles (per wj half): 8 glds16/wave ----
        #pragma unroll
        for (int sub = 0; sub < 2; ++sub) {
            const int j0 = jb + (ith * 2 + sub) * 64;
            unsigned short* Ks = &shm[sub * 16384 + wj * 8192];
            unsigned short* Vs = &shm[sub * 16384 + wj * 8192 + 4096];
            #pragma unroll
            for (int i = 0; i < 2; ++i) {
                const int row = wm * 16 + i * 8;       // wave-uniform
                glds16(kb  + kbase + (long)(j0 + row + sr8) * DH + scg * 8, Ks + row * 64);
                glds16(vtb + vbase + (long)(row + sr8) * SEQ + j0 + scg * 8, Vs + row * 64);
            }
        }
        __syncthreads();

        // ---- compute both subtiles back-to-back (identical per-sub math) ----
        #pragma unroll
        for (int sub = 0; sub < 2; ++sub) {
            const int it = ith * 2 + sub;
            const unsigned int bits0 = mb[(long)it * 64];
            const unsigned int bits1 = mb[(long)it * 64 + 2048];
            const unsigned short* Ks = &shm[sub * 16384 + wj * 8192];
            const unsigned short* Vs = &shm[sub * 16384 + wj * 8192 + 4096];

            // S^T = K Q^T both q-tiles; softmax fused; tile0 P -> LDS,
            // tile1 P packed in regs
            uint2 p1s[4];
            #pragma unroll
            for (int nt = 0; nt < 4; ++nt) {
                const int rbase = (nt * 16 + l16) * 64;
                const half8 k0 = *reinterpret_cast<const half8*>(&Ks[rbase + ((0 + g) ^ sw) * 8]);
                const half8 k1 = *reinterpret_cast<const half8*>(&Ks[rbase + (((4 + g) ^ sw) * 8)]);
                f32x4 s0 = {0.f, 0.f, 0.f, 0.f};
                f32x4 s1 = {0.f, 0.f, 0.f, 0.f};
                s0 = __builtin_amdgcn_mfma_f32_16x16x32_f16(k0, q0, s0, 0, 0, 0);
                s0 = __builtin_amdgcn_mfma_f32_16x16x32_f16(k1, q1, s0, 0, 0, 0);
                s1 = __builtin_amdgcn_mfma_f32_16x16x32_f16(k0, q2, s1, 0, 0, 0);
                s1 = __builtin_amdgcn_mfma_f32_16x16x32_f16(k1, q3, s1, 0, 0, 0);

                float pa[4], pb[4];
                #pragma unroll
                for (int r = 0; r < 4; ++r) {
                    const float e0 = __builtin_amdgcn_exp2f(s0[r]);
                    const float e1 = __builtin_amdgcn_exp2f(s1[r]);
                    pa[r] = ((bits0 >> (nt * 4 + r)) & 1u) ? e0 : 0.f;
                    pb[r] = ((bits1 >> (nt * 4 + r)) & 1u) ? e1 : 0.f;
                }
                const int poff = l16 * 64 + (((2 * nt + (g >> 1)) ^ sw) * 8) + (g & 1) * 4;
                uint2 pk0;
                pk0.x = pkrtz(pa[0], pa[1]);
                pk0.y = pkrtz(pa[2], pa[3]);
                *reinterpret_cast<uint2*>(&Pw[poff]) = pk0;
                p1s[nt].x = pkrtz(pb[0], pb[1]);
                p1s[nt].y = pkrtz(pb[2], pb[3]);
            }

            // tile0 P fragments, then overwrite Pw with tile1 (wave-private,
            // lgkm-ordered: reads complete before aliasing writes)
            const half8 pb00 = *reinterpret_cast<const half8*>(&Pw[l16 * 64 + ((0 + g) ^ sw) * 8]);
            const half8 pb01 = *reinterpret_cast<const half8*>(&Pw[l16 * 64 + (((4 + g) ^ sw) * 8)]);
            #pragma unroll
            for (int nt = 0; nt < 4; ++nt) {
                const int poff = l16 * 64 + (((2 * nt + (g >> 1)) ^ sw) * 8) + (g & 1) * 4;
                *reinterpret_cast<uint2*>(&Pw[poff]) = p1s[nt];
            }
            const half8 pb10 = *reinterpret_cast<const half8*>(&Pw[l16 * 64 + ((0 + g) ^ sw) * 8]);
            const half8 pb11 = *reinterpret_cast<const half8*>(&Pw[l16 * 64 + (((4 + g) ^ sw) * 8)]);

            // O^T += V^T P^T; V fragments read once, feed both q-tiles
            #pragma unroll
            for (int dt = 0; dt < 4; ++dt) {
                const int vb = (dt * 16 + l16) * 64;
                const half8 v0 = *reinterpret_cast<const half8*>(&Vs[vb + ((0 + g) ^ sw) * 8]);
                const half8 v1 = *reinterpret_cast<const half8*>(&Vs[vb + (((4 + g) ^ sw) * 8)]);
                o0[dt] = __builtin_amdgcn_mfma_f32_16x16x32_f16(v0, pb00, o0[dt], 0, 0, 0);
                o0[dt] = __builtin_amdgcn_mfma_f32_16x16x32_f16(v1, pb01, o0[dt], 0, 0, 0);
                o1[dt] = __builtin_amdgcn_mfma_f32_16x16x32_f16(v0, pb10, o1[dt], 0, 0, 0);
                o1[dt] = __builtin_amdgcn_mfma_f32_16x16x32_f16(v1, pb11, o1[dt], 0, 0, 0);
            }
            oz0 = __builtin_amdgcn_mfma_f32_16x16x32_f16(ones, pb00, oz0, 0, 0, 0);
            oz0 = __builtin_amdgcn_mfma_f32_16x16x32_f16(ones, pb01, oz0, 0, 0, 0);
            oz1 = __builtin_amdgcn_mfma_f32_16x16x32_f16(ones, pb10, oz1, 0, 0, 0);
            oz1 = __builtin_amdgcn_mfma_f32_16x16x32_f16(ones, pb11, oz1, 0, 0, 0);
        }
        __syncthreads();    // release both KV subtiles for next staging round
    }

    // ---- combine the two j-halves (linear partials) ----
    float* cmb = (float*)shm;               // 128*68 + 128 floats = 35 KB <= 80 KB
    const int ZOFF = 128 * 68;
    const int ci0  = wm * 32 + l16;
    const int ci1  = ci0 + 16;
    if (wj == 1) {
        #pragma unroll
        for (int dt = 0; dt < 4; ++dt) {
            *reinterpret_cast<f32x4*>(&cmb[ci0 * 68 + dt * 16 + g * 4]) = o0[dt];
            *reinterpret_cast<f32x4*>(&cmb[ci1 * 68 + dt * 16 + g * 4]) = o1[dt];
        }
        if (g == 0) {
            cmb[ZOFF + ci0] = oz0[0];
            cmb[ZOFF + ci1] = oz1[0];
        }
    }
    __syncthreads();
    if (wj == 0) {
        const float Z0   = oz0[0] + cmb[ZOFF + ci0];
        const float Z1   = oz1[0] + cmb[ZOFF + ci1];
        const float inv0 = 1.f / (Z0 + 1e-30f);
        const float inv1 = 1.f / (Z1 + 1e-30f);
        const long obase0 = ((long)bb * SEQ + myrow0 + l16) * DIM + h * DH;
        const long obase1 = obase0 + (long)16 * DIM;
        #pragma unroll
        for (int dt = 0; dt < 4; ++dt) {
            const f32x4 oc0 = *reinterpret_cast<const f32x4*>(&cmb[ci0 * 68 + dt * 16 + g * 4]);
            const f32x4 oc1 = *reinterpret_cast<const f32x4*>(&cmb[ci1 * 68 + dt * 16 + g * 4]);
            uint2 pk;
            pk.x = pkrtz((o0[dt][0] + oc0[0]) * inv0, (o0[dt][1] + oc0[1]) * inv0);
            pk.y = pkrtz((o0[dt][2] + oc0[2]) * inv0, (o0[dt][3] + oc0[3]) * inv0);
            *reinterpret_cast<uint2*>(zh + obase0 + dt * 16 + g * 4) = pk;
            pk.x = pkrtz((o1[dt][0] + oc1[0]) * inv1, (o1[dt][1] + oc1[1]) * inv1);
            pk.y = pkrtz((o1[dt][2] + oc1[2]) * inv1, (o1[dt][3] + oc1[3]) * inv1);
            *reinterpret_cast<uint2*>(zh + obase1 + dt * 16 + g * 4) = pk;
        }
    }
}

// ---------------------------------------------------------------------------
extern "C" void kernel_launch(void* const* d_in, const int* in_sizes, int n_in,
                              void* d_out, int out_size, void* d_ws, size_t ws_size,
                              hipStream_t stream) {
    const float* x     = (const float*)d_in[0];
    const float* mask  = (const float*)d_in[1];
    const float* W_qkv = (const float*)d_in[2];
    const float* W_out = (const float*)d_in[3];
    const float* b_out = (const float*)d_in[4];
    float* out = (float*)d_out;

    unsigned short* ws = (unsigned short*)d_ws;
    unsigned short* xh    = ws;                  // 4M fp16 (reused as z after gemm1)
    unsigned short* WqT   = xh    + 4194304;     // 3M fp16
    unsigned short* WoT   = WqT   + 3145728;     // 1M fp16
    unsigned short* qbu   = WoT   + 1048576;     // 4M fp16
    unsigned short* kbu   = qbu   + 4194304;     // 4M fp16
    unsigned short* vtb   = kbu   + 4194304;     // 4M fp16
    unsigned short* mbits = vtb   + 4194304;     // 0.5M -> 41 MB total
    unsigned short* zz    = xh;

    prepass<<<9216, 256, 0, stream>>>(x, xh, W_qkv, WqT, W_out, WoT, mask, mbits);

    gemm_qkv_f16<<<768, 256, 0, stream>>>(xh, WqT, qbu, kbu, vtb);

    attn_mfma<<<512, 512, 0, stream>>>(qbu, kbu, vtb, mbits, zz);

    gemm_out_f16<<<1024, 256, 0, stream>>>(zz, WoT, b_out, out);
}